// Round 9
// baseline (335.156 us; speedup 1.0000x reference)
//
#include <hip/hip_runtime.h>
#include <hip/hip_bf16.h>

typedef __attribute__((ext_vector_type(8))) short short8;
typedef __attribute__((ext_vector_type(4))) float f32x4;
typedef __attribute__((ext_vector_type(2))) float f32x2;

#define EPS 1e-5f

__device__ __forceinline__ unsigned short f2bf(float f) {
    union { float f; unsigned u; } v; v.f = f;
    unsigned u = v.u;
    u += 0x7FFFu + ((u >> 16) & 1u);   // RNE
    return (unsigned short)(u >> 16);
}
__device__ __forceinline__ float bflo(unsigned u) {
    union { unsigned u; float f; } v; v.u = u << 16; return v.f;
}
__device__ __forceinline__ float bfhi(unsigned u) {
    union { unsigned u; float f; } v; v.u = u & 0xffff0000u; return v.f;
}
__device__ __forceinline__ float bf2f(ushort u) {
    union { unsigned u; float f; } v; v.u = ((unsigned)u) << 16; return v.f;
}
__device__ __forceinline__ unsigned char f2fp8(float v) {
    return (unsigned char)(__builtin_amdgcn_cvt_pk_fp8_f32(v, v, 0, false) & 0xff);
}
__device__ __forceinline__ int sig(int p) {            // sigma: acc-layout k-permutation
    return (((p >> 2) & 1) << 4) | (((p >> 3) & 3) << 2) | (p & 3);
}

// load 8 consecutive f32, convert to a bf16x8 MFMA fragment
__device__ __forceinline__ short8 load_frag_f32(const float* __restrict__ p) {
    f32x4 a = *(const f32x4*)p;
    f32x4 b = *(const f32x4*)(p + 4);
    short8 r;
    r[0] = (short)f2bf(a[0]); r[1] = (short)f2bf(a[1]);
    r[2] = (short)f2bf(a[2]); r[3] = (short)f2bf(a[3]);
    r[4] = (short)f2bf(b[0]); r[5] = (short)f2bf(b[1]);
    r[6] = (short)f2bf(b[2]); r[7] = (short)f2bf(b[3]);
    return r;
}

// dot(q[0..16) bf16, k[0..16) fp8) for one head
__device__ __forceinline__ float dot16_q_k8(const ushort* q, const unsigned char* kp) {
    uint4 kw = *(const uint4*)kp;
    const unsigned* qd = (const unsigned*)q;
    f32x2 a, b; float s = 0.f;
    a = __builtin_amdgcn_cvt_pk_f32_fp8(kw.x, false);
    b = __builtin_amdgcn_cvt_pk_f32_fp8(kw.x, true);
    s += a[0]*bflo(qd[0]) + a[1]*bfhi(qd[0]) + b[0]*bflo(qd[1]) + b[1]*bfhi(qd[1]);
    a = __builtin_amdgcn_cvt_pk_f32_fp8(kw.y, false);
    b = __builtin_amdgcn_cvt_pk_f32_fp8(kw.y, true);
    s += a[0]*bflo(qd[2]) + a[1]*bfhi(qd[2]) + b[0]*bflo(qd[3]) + b[1]*bfhi(qd[3]);
    a = __builtin_amdgcn_cvt_pk_f32_fp8(kw.z, false);
    b = __builtin_amdgcn_cvt_pk_f32_fp8(kw.z, true);
    s += a[0]*bflo(qd[4]) + a[1]*bfhi(qd[4]) + b[0]*bflo(qd[5]) + b[1]*bfhi(qd[5]);
    a = __builtin_amdgcn_cvt_pk_f32_fp8(kw.w, false);
    b = __builtin_amdgcn_cvt_pk_f32_fp8(kw.w, true);
    s += a[0]*bflo(qd[6]) + a[1]*bfhi(qd[6]) + b[0]*bflo(qd[7]) + b[1]*bfhi(qd[7]);
    return s;
}

// ---------------- K0: weight transforms only (x conversion moved to k_qkv) -
// wcat = 18 contiguous 16KB chunks for k_tail's LDS ring:
//   chunk 0: out_w cols 0..63  image (slot-xor, 8 slots/row, 128B/row)
//   chunk 1: out_w cols 64..127 image
//   chunk 2+kb: [w1 kb-chunk image (8KB, sigma+xor) | w2 kb-chunk (8KB, chunk-major sigma)]
__global__ __launch_bounds__(256) void k_prep(
        const float* __restrict__ ipw, const float* __restrict__ ow,
        const float* __restrict__ w1, const float* __restrict__ w2,
        ushort* __restrict__ wqb, ushort* __restrict__ wcat) {
    int i = blockIdx.x * 256 + threadIdx.x;
    if (i < 49152) wqb[i] = f2bf(ipw[i]);
    if (i < 147456) {
        float v;
        if (i < 8192) {
            int r = i >> 6, s = (i >> 3) & 7, e = i & 7;
            v = ow[r*128 + ((s ^ (r & 7)) << 3) + e];
        } else if (i < 16384) {
            int j = i - 8192;
            int r = j >> 6, s = (j >> 3) & 7, e = j & 7;
            v = ow[r*128 + 64 + ((s ^ (r & 7)) << 3) + e];
        } else {
            int j = i - 16384;
            int kb = j >> 13, o = j & 8191;
            if (o < 4096) {
                int r = (o >> 7) & 31, k16 = (o >> 3) & 15, e = o & 7;
                int cp = ((k16 ^ (r & 7)) << 3) + e;
                int cs = (cp & ~31) | sig(cp & 31);
                v = w1[(kb*32 + r)*128 + cs];
            } else {
                int oo = o - 4096;
                int ch = (oo >> 10) & 3, rw = (oo >> 3) & 127, e = oo & 7;
                v = w2[rw*512 + kb*32 + sig(ch*8 + e)];
            }
        }
        wcat[i] = f2bf(v);
    }
}

// ---------------- K1: qkv projection; reads x f32, emits xb + qt + kv8 -----
__global__ __launch_bounds__(256) void k_qkv(
        const float* __restrict__ x, const ushort* __restrict__ w,
        const float* __restrict__ bias, ushort* __restrict__ qt,
        unsigned char* __restrict__ kv8, ushort* __restrict__ xb, int N) {
    const int wave = threadIdx.x >> 6, lane = threadIdx.x & 63;
    const int l16 = lane & 15, l4 = lane >> 4;
    const int base = blockIdx.x * 64;

    short8 af[4][4];
    #pragma unroll
    for (int mt = 0; mt < 4; ++mt) {
        int row = base + mt*16 + l16;
        int rc = row < N ? row : N - 1;
        const float* p = x + (size_t)rc*128 + l4*8;
        #pragma unroll
        for (int kb = 0; kb < 4; ++kb) af[mt][kb] = load_frag_f32(p + kb*32);
    }
    // emit xb (bf16 x) from the fragments already in registers
    #pragma unroll
    for (int mt = 0; mt < 4; ++mt) {
        int row = base + mt*16 + l16;
        if (row < N) {
            #pragma unroll
            for (int kb = 0; kb < 4; ++kb)
                *(short8*)(xb + (size_t)row*128 + kb*32 + l4*8) = af[mt][kb];
        }
    }
    #pragma unroll
    for (int i = 0; i < 6; ++i) {
        int col = (wave*6 + i)*16 + l16;
        const ushort* pw = w + (size_t)col*128 + l4*8;
        short8 bf[4];
        #pragma unroll
        for (int kb = 0; kb < 4; ++kb) bf[kb] = *(const short8*)(pw + kb*32);
        float bv = bias[col];
        #pragma unroll
        for (int mt = 0; mt < 4; ++mt) {
            f32x4 acc = {0.f, 0.f, 0.f, 0.f};
            #pragma unroll
            for (int kb = 0; kb < 4; ++kb)
                acc = __builtin_amdgcn_mfma_f32_16x16x32_bf16(af[mt][kb], bf[kb], acc, 0, 0, 0);
            #pragma unroll
            for (int r = 0; r < 4; ++r) {
                int row = base + mt*16 + l4*4 + r;
                if (row < N) {
                    float v = acc[r] + bv;
                    if (col < 128) qt[(size_t)row*128 + col] = f2bf(v);
                    else kv8[(size_t)row*256 + (col - 128)] = f2fp8(v);
                }
            }
        }
    }
}

// ---------------- K2: sampled attention, fp8 K/V gather (unchanged) --------
__global__ __launch_bounds__(256) void k_attn(
        ushort* __restrict__ qt, const unsigned char* __restrict__ kv8,
        const int* __restrict__ samp, int N) {
    __shared__ float aw[4][8][17];              // [wave][head][k], padded
    __shared__ int   ai[4][16];                 // [wave][k] sample idx
    const int wave = threadIdx.x >> 6, lane = threadIdx.x & 63;
    const int n = blockIdx.x * 4 + wave;
    if (n >= N) return;
    const int k  = lane & 15;
    const int hp = lane >> 4;
    const int h0 = hp, h1 = hp + 4;

    const int idx = samp[(size_t)n*16 + k];
    const ushort* qrow = qt + (size_t)n*128;
    const unsigned char* krow = kv8 + (size_t)idx*256;

    float s0 = dot16_q_k8(qrow + h0*16, krow + h0*16);
    float s1 = dot16_q_k8(qrow + h1*16, krow + h1*16);
    s0 *= 0.25f; s1 *= 0.25f;     // 1/sqrt(16)
    float m0 = s0, m1 = s1;
    #pragma unroll
    for (int off = 1; off < 16; off <<= 1) {
        m0 = fmaxf(m0, __shfl_xor(m0, off));
        m1 = fmaxf(m1, __shfl_xor(m1, off));
    }
    float e0 = __expf(s0 - m0), e1 = __expf(s1 - m1);
    float d0 = e0, d1 = e1;
    #pragma unroll
    for (int off = 1; off < 16; off <<= 1) {
        d0 += __shfl_xor(d0, off);
        d1 += __shfl_xor(d1, off);
    }
    aw[wave][h0][k] = e0 / d0;
    aw[wave][h1][k] = e1 / d1;
    if (hp == 0) ai[wave][k] = idx;

    const int c = lane & 15;
    const int g = lane >> 4;
    const int h = c >> 1;

    int rows[4];
    #pragma unroll
    for (int b = 0; b < 4; ++b) rows[b] = ai[wave][g + b*4];
    uint2 vv[4];
    #pragma unroll
    for (int b = 0; b < 4; ++b)
        vv[b] = *(const uint2*)(kv8 + (size_t)(unsigned)rows[b]*256 + 128 + c*8);
    float wk[4];
    #pragma unroll
    for (int b = 0; b < 4; ++b) wk[b] = aw[wave][h][g + b*4];

    float a8[8] = {0.f,0.f,0.f,0.f,0.f,0.f,0.f,0.f};
    #pragma unroll
    for (int b = 0; b < 4; ++b) {
        f32x2 p;
        p = __builtin_amdgcn_cvt_pk_f32_fp8(vv[b].x, false);
        a8[0] = fmaf(wk[b], p[0], a8[0]); a8[1] = fmaf(wk[b], p[1], a8[1]);
        p = __builtin_amdgcn_cvt_pk_f32_fp8(vv[b].x, true);
        a8[2] = fmaf(wk[b], p[0], a8[2]); a8[3] = fmaf(wk[b], p[1], a8[3]);
        p = __builtin_amdgcn_cvt_pk_f32_fp8(vv[b].y, false);
        a8[4] = fmaf(wk[b], p[0], a8[4]); a8[5] = fmaf(wk[b], p[1], a8[5]);
        p = __builtin_amdgcn_cvt_pk_f32_fp8(vv[b].y, true);
        a8[6] = fmaf(wk[b], p[0], a8[6]); a8[7] = fmaf(wk[b], p[1], a8[7]);
    }
    #pragma unroll
    for (int i = 0; i < 8; ++i) {
        a8[i] += __shfl_xor(a8[i], 16);
        a8[i] += __shfl_xor(a8[i], 32);
    }
    if (lane < 16) {
        uint4 pack;
        pack.x = (unsigned)f2bf(a8[0]) | ((unsigned)f2bf(a8[1]) << 16);
        pack.y = (unsigned)f2bf(a8[2]) | ((unsigned)f2bf(a8[3]) << 16);
        pack.z = (unsigned)f2bf(a8[4]) | ((unsigned)f2bf(a8[5]) << 16);
        pack.w = (unsigned)f2bf(a8[6]) | ((unsigned)f2bf(a8[7]) << 16);
        *(uint4*)(qt + (size_t)n*128 + c*8) = pack;   // ctx over dead q row
    }
}

// ---------------- K3: fused tail, 32KB LDS ring, write-early/load-early ----
// 18 chunk-phases: 2 oproj halves + 16 FFN kb. Per phase p:
//   WRITE(p+1) (regs loaded a full phase ago; targets non-compute slot)
//   LOAD(p+2)  (flies across this whole compute phase before any barrier)
//   COMPUTE(p) from slot p&1; __syncthreads()
__global__ __launch_bounds__(256, 4) void k_tail(
        const ushort* __restrict__ ctx, const float* __restrict__ ob,
        const ushort* __restrict__ xb,
        const float* __restrict__ g1, const float* __restrict__ be1,
        const ushort* __restrict__ wcat, const float* __restrict__ b1,
        const float* __restrict__ b2,
        const float* __restrict__ g2, const float* __restrict__ be2,
        float* __restrict__ out, int N) {
    __shared__ __align__(16) char smem[32768];
    const int tid = threadIdx.x;
    const int lane = tid & 63;
    const int l16 = lane & 15, l4 = lane >> 4;
    const int base = blockIdx.x * 128 + (tid >> 6) * 32;
    int row[2], rc[2];
    row[0] = base + l16;       rc[0] = row[0] < N ? row[0] : N - 1;
    row[1] = base + 16 + l16;  rc[1] = row[1] < N ? row[1] : N - 1;

    uint4 nx0, nx1, nx2, nx3;
    const uint4* wc4 = (const uint4*)wcat;
#define STAGE_LOAD(cidx) { const uint4* s4 = wc4 + (cidx)*1024; \
    nx0 = s4[tid]; nx1 = s4[256 + tid]; nx2 = s4[512 + tid]; nx3 = s4[768 + tid]; }
#define STAGE_WRITE(cidx) { char* d = smem + (((cidx)&1) << 14); \
    *(uint4*)(d + tid*16) = nx0; *(uint4*)(d + (256 + tid)*16) = nx1; \
    *(uint4*)(d + (512 + tid)*16) = nx2; *(uint4*)(d + (768 + tid)*16) = nx3; }

    // prologue
    STAGE_LOAD(0); STAGE_WRITE(0); STAGE_LOAD(1);
    __syncthreads();

    f32x4 acc[2][8];
    #pragma unroll
    for (int mt = 0; mt < 2; ++mt)
        #pragma unroll
        for (int nt = 0; nt < 8; ++nt) acc[mt][nt] = (f32x4){0.f,0.f,0.f,0.f};

    // ---- phases 0,1: out-proj, K split in two halves ----
    #pragma unroll
    for (int ph = 0; ph < 2; ++ph) {
        STAGE_WRITE(ph + 1); STAGE_LOAD(ph + 2);
        short8 cfp[2][2];
        #pragma unroll
        for (int mt = 0; mt < 2; ++mt)
            #pragma unroll
            for (int j = 0; j < 2; ++j)
                cfp[mt][j] = *(const short8*)(ctx + (size_t)rc[mt]*128 + (ph*2 + j)*32 + l4*8);
        char* cur = smem + ((ph & 1) << 14);
        #pragma unroll
        for (int nt = 0; nt < 8; ++nt) {
            #pragma unroll
            for (int j = 0; j < 2; ++j) {
                int slot = (j*4 + l4) ^ (l16 & 7);
                short8 wf = *(const short8*)(cur + (nt*16 + l16)*128 + slot*16);
                acc[0][nt] = __builtin_amdgcn_mfma_f32_16x16x32_bf16(wf, cfp[0][j], acc[0][nt], 0, 0, 0);
                acc[1][nt] = __builtin_amdgcn_mfma_f32_16x16x32_bf16(wf, cfp[1][j], acc[1][nt], 0, 0, 0);
            }
        }
        __syncthreads();
    }

    // ---- bias + residual + LN1 -> yfrag ----
    float sum0 = 0.f, sq0 = 0.f, sum1 = 0.f, sq1 = 0.f;
    #pragma unroll
    for (int nt = 0; nt < 8; ++nt) {
        f32x4 obv = *(const f32x4*)(ob + nt*16 + l4*4);
        uint2 xr0 = *(const uint2*)(xb + (size_t)rc[0]*128 + nt*16 + l4*4);
        uint2 xr1 = *(const uint2*)(xb + (size_t)rc[1]*128 + nt*16 + l4*4);
        acc[0][nt][0] += obv[0] + bflo(xr0.x);
        acc[0][nt][1] += obv[1] + bfhi(xr0.x);
        acc[0][nt][2] += obv[2] + bflo(xr0.y);
        acc[0][nt][3] += obv[3] + bfhi(xr0.y);
        acc[1][nt][0] += obv[0] + bflo(xr1.x);
        acc[1][nt][1] += obv[1] + bfhi(xr1.x);
        acc[1][nt][2] += obv[2] + bflo(xr1.y);
        acc[1][nt][3] += obv[3] + bfhi(xr1.y);
        #pragma unroll
        for (int r = 0; r < 4; ++r) {
            sum0 += acc[0][nt][r]; sq0 += acc[0][nt][r]*acc[0][nt][r];
            sum1 += acc[1][nt][r]; sq1 += acc[1][nt][r]*acc[1][nt][r];
        }
    }
    sum0 += __shfl_xor(sum0, 16); sum0 += __shfl_xor(sum0, 32);
    sq0  += __shfl_xor(sq0, 16);  sq0  += __shfl_xor(sq0, 32);
    sum1 += __shfl_xor(sum1, 16); sum1 += __shfl_xor(sum1, 32);
    sq1  += __shfl_xor(sq1, 16);  sq1  += __shfl_xor(sq1, 32);
    float mean[2], rstd[2];
    mean[0] = sum0 * (1.f/128.f);
    rstd[0] = rsqrtf(sq0*(1.f/128.f) - mean[0]*mean[0] + EPS);
    mean[1] = sum1 * (1.f/128.f);
    rstd[1] = rsqrtf(sq1*(1.f/128.f) - mean[1]*mean[1] + EPS);

    short8 yfrag[2][4];
    #pragma unroll
    for (int nt = 0; nt < 8; ++nt) {
        f32x4 gv = *(const f32x4*)(g1 + nt*16 + l4*4);
        f32x4 bv = *(const f32x4*)(be1 + nt*16 + l4*4);
        #pragma unroll
        for (int mt = 0; mt < 2; ++mt)
            #pragma unroll
            for (int r = 0; r < 4; ++r) {
                float yn = (acc[mt][nt][r] - mean[mt]) * rstd[mt] * gv[r] + bv[r];
                yfrag[mt][nt >> 1][(nt & 1)*4 + r] = (short)f2bf(yn);
            }
    }

    // ---- FFN: phases 2..17 (kb = p-2), acc reused as acc2 ----
    f32x4 (&acc2)[2][8] = acc;
    #pragma unroll
    for (int mt = 0; mt < 2; ++mt)
        #pragma unroll
        for (int nt = 0; nt < 8; ++nt) acc2[mt][nt] = (f32x4){0.f,0.f,0.f,0.f};

    #pragma unroll 2
    for (int p = 2; p < 18; ++p) {
        if (p <= 16) { STAGE_WRITE(p + 1); }
        if (p <= 15) { STAGE_LOAD(p + 2); }
        const int kb = p - 2;
        char* cur = smem + ((p & 1) << 14);
        short8 wA[4], wB[4];
        #pragma unroll
        for (int c = 0; c < 4; ++c) {
            int slot = (c*4 + l4) ^ (l16 & 7);
            wA[c] = *(const short8*)(cur + l16*256 + slot*16);
            wB[c] = *(const short8*)(cur + 4096 + l16*256 + slot*16);
        }
        f32x4 hA[2] = {{0.f,0.f,0.f,0.f},{0.f,0.f,0.f,0.f}};
        f32x4 hB[2] = {{0.f,0.f,0.f,0.f},{0.f,0.f,0.f,0.f}};
        #pragma unroll
        for (int c = 0; c < 4; ++c)
            #pragma unroll
            for (int mt = 0; mt < 2; ++mt) {
                hA[mt] = __builtin_amdgcn_mfma_f32_16x16x32_bf16(wA[c], yfrag[mt][c], hA[mt], 0, 0, 0);
                hB[mt] = __builtin_amdgcn_mfma_f32_16x16x32_bf16(wB[c], yfrag[mt][c], hB[mt], 0, 0, 0);
            }
        f32x4 bA = *(const f32x4*)(b1 + kb*32 + l4*4);
        f32x4 bB = *(const f32x4*)(b1 + kb*32 + 16 + l4*4);
        short8 hf[2];
        #pragma unroll
        for (int mt = 0; mt < 2; ++mt)
            #pragma unroll
            for (int r = 0; r < 4; ++r) {
                float vA = hA[mt][r] + bA[r]; vA = vA > 0.f ? vA : 0.f;
                float vB = hB[mt][r] + bB[r]; vB = vB > 0.f ? vB : 0.f;
                hf[mt][r]     = (short)f2bf(vA);
                hf[mt][4 + r] = (short)f2bf(vB);
            }
        #pragma unroll
        for (int nt = 0; nt < 8; ++nt) {
            short8 w2f = *(const short8*)(cur + 8192 + l4*2048 + (nt*16 + l16)*16);
            acc2[0][nt] = __builtin_amdgcn_mfma_f32_16x16x32_bf16(w2f, hf[0], acc2[0][nt], 0, 0, 0);
            acc2[1][nt] = __builtin_amdgcn_mfma_f32_16x16x32_bf16(w2f, hf[1], acc2[1][nt], 0, 0, 0);
        }
        if (p < 17) __syncthreads();
    }

    // ---- s = y + ff + b2, LN2, coalesced float4 out ----
    #pragma unroll
    for (int mt = 0; mt < 2; ++mt) {
        float sum2 = 0.f, sq2 = 0.f;
        #pragma unroll
        for (int nt = 0; nt < 8; ++nt) {
            f32x4 b2v = *(const f32x4*)(b2 + nt*16 + l4*4);
            #pragma unroll
            for (int r = 0; r < 4; ++r) {
                float s = bf2f((ushort)yfrag[mt][nt >> 1][(nt & 1)*4 + r]) + acc2[mt][nt][r] + b2v[r];
                acc2[mt][nt][r] = s; sum2 += s; sq2 += s*s;
            }
        }
        sum2 += __shfl_xor(sum2, 16); sum2 += __shfl_xor(sum2, 32);
        sq2  += __shfl_xor(sq2, 16);  sq2  += __shfl_xor(sq2, 32);
        float mean2 = sum2 * (1.f/128.f);
        float rstd2 = rsqrtf(sq2*(1.f/128.f) - mean2*mean2 + EPS);
        if (row[mt] < N) {
            #pragma unroll
            for (int nt = 0; nt < 8; ++nt) {
                f32x4 gv = *(const f32x4*)(g2 + nt*16 + l4*4);
                f32x4 bv = *(const f32x4*)(be2 + nt*16 + l4*4);
                f32x4 o;
                #pragma unroll
                for (int r = 0; r < 4; ++r)
                    o[r] = (acc2[mt][nt][r] - mean2) * rstd2 * gv[r] + bv[r];
                *(f32x4*)(out + (size_t)row[mt]*128 + nt*16 + l4*4) = o;
            }
        }
    }
#undef STAGE_LOAD
#undef STAGE_WRITE
}

extern "C" void kernel_launch(void* const* d_in, const int* in_sizes, int n_in,
                              void* d_out, int out_size, void* d_ws, size_t ws_size,
                              hipStream_t stream) {
    (void)n_in; (void)out_size; (void)ws_size;
    const float* x   = (const float*)d_in[0];
    const int*   smp = (const int*)  d_in[1];
    const float* ipw = (const float*)d_in[2];
    const float* ipb = (const float*)d_in[3];
    const float* ow  = (const float*)d_in[4];
    const float* ob  = (const float*)d_in[5];
    const float* w1  = (const float*)d_in[6];
    const float* b1  = (const float*)d_in[7];
    const float* w2  = (const float*)d_in[8];
    const float* b2  = (const float*)d_in[9];
    const float* g1  = (const float*)d_in[10];
    const float* be1 = (const float*)d_in[11];
    const float* g2  = (const float*)d_in[12];
    const float* be2 = (const float*)d_in[13];
    const int N = in_sizes[0] / 128;

    ushort* qt   = (ushort*)d_ws;                   // [N][128] bf16 q, then ctx
    unsigned char* kv8 = (unsigned char*)(qt + (size_t)N*128);  // [N][256] fp8 K|V
    ushort* wqb  = (ushort*)(kv8 + (size_t)N*256);  // 384*128 natural bf16
    ushort* wcat = wqb + 384*128;                   // 18*8192 chunk stream
    ushort* xb   = wcat + 18*8192;                  // [N][128] bf16 x
    float*  outp = (float*)d_out;

    k_prep <<<576,         256, 0, stream>>>(ipw, ow, w1, w2, wqb, wcat);
    k_qkv  <<<(N+63)/64,   256, 0, stream>>>(x, wqb, ipb, qt, kv8, xb, N);
    k_attn <<<(N+3)/4,     256, 0, stream>>>(qt, kv8, smp, N);
    k_tail <<<(N+127)/128, 256, 0, stream>>>(qt, ob, xb, g1, be1,
                                             wcat, b1, b2, g2, be2, outp, N);
}

// Round 10
// 236.451 us; speedup vs baseline: 1.4174x; 1.4174x over previous
//
#include <hip/hip_runtime.h>
#include <hip/hip_bf16.h>

typedef __attribute__((ext_vector_type(8))) short short8;
typedef __attribute__((ext_vector_type(4))) float f32x4;
typedef __attribute__((ext_vector_type(2))) float f32x2;

#define EPS 1e-5f

__device__ __forceinline__ unsigned short f2bf(float f) {
    union { float f; unsigned u; } v; v.f = f;
    unsigned u = v.u;
    u += 0x7FFFu + ((u >> 16) & 1u);   // RNE
    return (unsigned short)(u >> 16);
}
__device__ __forceinline__ float bflo(unsigned u) {
    union { unsigned u; float f; } v; v.u = u << 16; return v.f;
}
__device__ __forceinline__ float bfhi(unsigned u) {
    union { unsigned u; float f; } v; v.u = u & 0xffff0000u; return v.f;
}
__device__ __forceinline__ float bf2f(ushort u) {
    union { unsigned u; float f; } v; v.u = ((unsigned)u) << 16; return v.f;
}
__device__ __forceinline__ unsigned char f2fp8(float v) {
    return (unsigned char)(__builtin_amdgcn_cvt_pk_fp8_f32(v, v, 0, false) & 0xff);
}
__device__ __forceinline__ int sig(int p) {            // sigma: acc-layout k-permutation
    return (((p >> 2) & 1) << 4) | (((p >> 3) & 3) << 2) | (p & 3);
}

// load 8 consecutive f32, convert to a bf16x8 MFMA fragment
__device__ __forceinline__ short8 load_frag_f32(const float* __restrict__ p) {
    f32x4 a = *(const f32x4*)p;
    f32x4 b = *(const f32x4*)(p + 4);
    short8 r;
    r[0] = (short)f2bf(a[0]); r[1] = (short)f2bf(a[1]);
    r[2] = (short)f2bf(a[2]); r[3] = (short)f2bf(a[3]);
    r[4] = (short)f2bf(b[0]); r[5] = (short)f2bf(b[1]);
    r[6] = (short)f2bf(b[2]); r[7] = (short)f2bf(b[3]);
    return r;
}

// dot(q[0..16) bf16, k[0..16) fp8) for one head
__device__ __forceinline__ float dot16_q_k8(const ushort* q, const unsigned char* kp) {
    uint4 kw = *(const uint4*)kp;
    const unsigned* qd = (const unsigned*)q;
    f32x2 a, b; float s = 0.f;
    a = __builtin_amdgcn_cvt_pk_f32_fp8(kw.x, false);
    b = __builtin_amdgcn_cvt_pk_f32_fp8(kw.x, true);
    s += a[0]*bflo(qd[0]) + a[1]*bfhi(qd[0]) + b[0]*bflo(qd[1]) + b[1]*bfhi(qd[1]);
    a = __builtin_amdgcn_cvt_pk_f32_fp8(kw.y, false);
    b = __builtin_amdgcn_cvt_pk_f32_fp8(kw.y, true);
    s += a[0]*bflo(qd[2]) + a[1]*bfhi(qd[2]) + b[0]*bflo(qd[3]) + b[1]*bfhi(qd[3]);
    a = __builtin_amdgcn_cvt_pk_f32_fp8(kw.z, false);
    b = __builtin_amdgcn_cvt_pk_f32_fp8(kw.z, true);
    s += a[0]*bflo(qd[4]) + a[1]*bfhi(qd[4]) + b[0]*bflo(qd[5]) + b[1]*bfhi(qd[5]);
    a = __builtin_amdgcn_cvt_pk_f32_fp8(kw.w, false);
    b = __builtin_amdgcn_cvt_pk_f32_fp8(kw.w, true);
    s += a[0]*bflo(qd[6]) + a[1]*bfhi(qd[6]) + b[0]*bflo(qd[7]) + b[1]*bfhi(qd[7]);
    return s;
}

// ---------------- K0: weight transforms only -------------------------------
// wcat = 18 contiguous 16KB chunks for k_tail's LDS ring:
//   chunk 0: out_w cols 0..63  image (slot-xor, 8 slots/row, 128B/row)
//   chunk 1: out_w cols 64..127 image
//   chunk 2+kb: [w1 kb-chunk image (8KB, sigma+xor) | w2 kb-chunk (8KB, chunk-major sigma)]
__global__ __launch_bounds__(256) void k_prep(
        const float* __restrict__ ipw, const float* __restrict__ ow,
        const float* __restrict__ w1, const float* __restrict__ w2,
        ushort* __restrict__ wqb, ushort* __restrict__ wcat) {
    int i = blockIdx.x * 256 + threadIdx.x;
    if (i < 49152) wqb[i] = f2bf(ipw[i]);
    if (i < 147456) {
        float v;
        if (i < 8192) {
            int r = i >> 6, s = (i >> 3) & 7, e = i & 7;
            v = ow[r*128 + ((s ^ (r & 7)) << 3) + e];
        } else if (i < 16384) {
            int j = i - 8192;
            int r = j >> 6, s = (j >> 3) & 7, e = j & 7;
            v = ow[r*128 + 64 + ((s ^ (r & 7)) << 3) + e];
        } else {
            int j = i - 16384;
            int kb = j >> 13, o = j & 8191;
            if (o < 4096) {
                int r = (o >> 7) & 31, k16 = (o >> 3) & 15, e = o & 7;
                int cp = ((k16 ^ (r & 7)) << 3) + e;
                int cs = (cp & ~31) | sig(cp & 31);
                v = w1[(kb*32 + r)*128 + cs];
            } else {
                int oo = o - 4096;
                int ch = (oo >> 10) & 3, rw = (oo >> 3) & 127, e = oo & 7;
                v = w2[rw*512 + kb*32 + sig(ch*8 + e)];
            }
        }
        wcat[i] = f2bf(v);
    }
}

// ---------------- K1: qkv projection; reads x f32, emits xb + qt + kv8 -----
__global__ __launch_bounds__(256) void k_qkv(
        const float* __restrict__ x, const ushort* __restrict__ w,
        const float* __restrict__ bias, ushort* __restrict__ qt,
        unsigned char* __restrict__ kv8, ushort* __restrict__ xb, int N) {
    const int wave = threadIdx.x >> 6, lane = threadIdx.x & 63;
    const int l16 = lane & 15, l4 = lane >> 4;
    const int base = blockIdx.x * 64;

    short8 af[4][4];
    #pragma unroll
    for (int mt = 0; mt < 4; ++mt) {
        int row = base + mt*16 + l16;
        int rc = row < N ? row : N - 1;
        const float* p = x + (size_t)rc*128 + l4*8;
        #pragma unroll
        for (int kb = 0; kb < 4; ++kb) af[mt][kb] = load_frag_f32(p + kb*32);
    }
    // emit xb (bf16 x) from the fragments already in registers
    #pragma unroll
    for (int mt = 0; mt < 4; ++mt) {
        int row = base + mt*16 + l16;
        if (row < N) {
            #pragma unroll
            for (int kb = 0; kb < 4; ++kb)
                *(short8*)(xb + (size_t)row*128 + kb*32 + l4*8) = af[mt][kb];
        }
    }
    #pragma unroll
    for (int i = 0; i < 6; ++i) {
        int col = (wave*6 + i)*16 + l16;
        const ushort* pw = w + (size_t)col*128 + l4*8;
        short8 bf[4];
        #pragma unroll
        for (int kb = 0; kb < 4; ++kb) bf[kb] = *(const short8*)(pw + kb*32);
        float bv = bias[col];
        #pragma unroll
        for (int mt = 0; mt < 4; ++mt) {
            f32x4 acc = {0.f, 0.f, 0.f, 0.f};
            #pragma unroll
            for (int kb = 0; kb < 4; ++kb)
                acc = __builtin_amdgcn_mfma_f32_16x16x32_bf16(af[mt][kb], bf[kb], acc, 0, 0, 0);
            #pragma unroll
            for (int r = 0; r < 4; ++r) {
                int row = base + mt*16 + l4*4 + r;
                if (row < N) {
                    float v = acc[r] + bv;
                    if (col < 128) qt[(size_t)row*128 + col] = f2bf(v);
                    else kv8[(size_t)row*256 + (col - 128)] = f2fp8(v);
                }
            }
        }
    }
}

// ---------------- K2: sampled attention, fp8 K/V gather (unchanged) --------
__global__ __launch_bounds__(256) void k_attn(
        ushort* __restrict__ qt, const unsigned char* __restrict__ kv8,
        const int* __restrict__ samp, int N) {
    __shared__ float aw[4][8][17];              // [wave][head][k], padded
    __shared__ int   ai[4][16];                 // [wave][k] sample idx
    const int wave = threadIdx.x >> 6, lane = threadIdx.x & 63;
    const int n = blockIdx.x * 4 + wave;
    if (n >= N) return;
    const int k  = lane & 15;
    const int hp = lane >> 4;
    const int h0 = hp, h1 = hp + 4;

    const int idx = samp[(size_t)n*16 + k];
    const ushort* qrow = qt + (size_t)n*128;
    const unsigned char* krow = kv8 + (size_t)idx*256;

    float s0 = dot16_q_k8(qrow + h0*16, krow + h0*16);
    float s1 = dot16_q_k8(qrow + h1*16, krow + h1*16);
    s0 *= 0.25f; s1 *= 0.25f;     // 1/sqrt(16)
    float m0 = s0, m1 = s1;
    #pragma unroll
    for (int off = 1; off < 16; off <<= 1) {
        m0 = fmaxf(m0, __shfl_xor(m0, off));
        m1 = fmaxf(m1, __shfl_xor(m1, off));
    }
    float e0 = __expf(s0 - m0), e1 = __expf(s1 - m1);
    float d0 = e0, d1 = e1;
    #pragma unroll
    for (int off = 1; off < 16; off <<= 1) {
        d0 += __shfl_xor(d0, off);
        d1 += __shfl_xor(d1, off);
    }
    aw[wave][h0][k] = e0 / d0;
    aw[wave][h1][k] = e1 / d1;
    if (hp == 0) ai[wave][k] = idx;

    const int c = lane & 15;
    const int g = lane >> 4;
    const int h = c >> 1;

    int rows[4];
    #pragma unroll
    for (int b = 0; b < 4; ++b) rows[b] = ai[wave][g + b*4];
    uint2 vv[4];
    #pragma unroll
    for (int b = 0; b < 4; ++b)
        vv[b] = *(const uint2*)(kv8 + (size_t)(unsigned)rows[b]*256 + 128 + c*8);
    float wk[4];
    #pragma unroll
    for (int b = 0; b < 4; ++b) wk[b] = aw[wave][h][g + b*4];

    float a8[8] = {0.f,0.f,0.f,0.f,0.f,0.f,0.f,0.f};
    #pragma unroll
    for (int b = 0; b < 4; ++b) {
        f32x2 p;
        p = __builtin_amdgcn_cvt_pk_f32_fp8(vv[b].x, false);
        a8[0] = fmaf(wk[b], p[0], a8[0]); a8[1] = fmaf(wk[b], p[1], a8[1]);
        p = __builtin_amdgcn_cvt_pk_f32_fp8(vv[b].x, true);
        a8[2] = fmaf(wk[b], p[0], a8[2]); a8[3] = fmaf(wk[b], p[1], a8[3]);
        p = __builtin_amdgcn_cvt_pk_f32_fp8(vv[b].y, false);
        a8[4] = fmaf(wk[b], p[0], a8[4]); a8[5] = fmaf(wk[b], p[1], a8[5]);
        p = __builtin_amdgcn_cvt_pk_f32_fp8(vv[b].y, true);
        a8[6] = fmaf(wk[b], p[0], a8[6]); a8[7] = fmaf(wk[b], p[1], a8[7]);
    }
    #pragma unroll
    for (int i = 0; i < 8; ++i) {
        a8[i] += __shfl_xor(a8[i], 16);
        a8[i] += __shfl_xor(a8[i], 32);
    }
    if (lane < 16) {
        uint4 pack;
        pack.x = (unsigned)f2bf(a8[0]) | ((unsigned)f2bf(a8[1]) << 16);
        pack.y = (unsigned)f2bf(a8[2]) | ((unsigned)f2bf(a8[3]) << 16);
        pack.z = (unsigned)f2bf(a8[4]) | ((unsigned)f2bf(a8[5]) << 16);
        pack.w = (unsigned)f2bf(a8[6]) | ((unsigned)f2bf(a8[7]) << 16);
        *(uint4*)(qt + (size_t)n*128 + c*8) = pack;   // ctx over dead q row
    }
}

// ---------------- K3: fused tail, 32KB LDS ring, write-early/load-early ----
// 18 chunk-phases: 2 oproj halves + 16 FFN kb. Per phase p:
//   WRITE(p+1) (regs loaded a full phase ago; targets non-compute slot)
//   LOAD(p+2)  (flies across this whole compute phase before any barrier)
//   COMPUTE(p) from slot p&1; __syncthreads()
// NOTE: plain launch_bounds — (256,4) in R9 capped VGPR at 64 and spilled
// ~340MB to scratch (WRITE_SIZE 392MB). Registers win over occupancy here.
__global__ __launch_bounds__(256) void k_tail(
        const ushort* __restrict__ ctx, const float* __restrict__ ob,
        const ushort* __restrict__ xb,
        const float* __restrict__ g1, const float* __restrict__ be1,
        const ushort* __restrict__ wcat, const float* __restrict__ b1,
        const float* __restrict__ b2,
        const float* __restrict__ g2, const float* __restrict__ be2,
        float* __restrict__ out, int N) {
    __shared__ __align__(16) char smem[32768];
    const int tid = threadIdx.x;
    const int lane = tid & 63;
    const int l16 = lane & 15, l4 = lane >> 4;
    const int base = blockIdx.x * 128 + (tid >> 6) * 32;
    int row[2], rc[2];
    row[0] = base + l16;       rc[0] = row[0] < N ? row[0] : N - 1;
    row[1] = base + 16 + l16;  rc[1] = row[1] < N ? row[1] : N - 1;

    uint4 nx0, nx1, nx2, nx3;
    const uint4* wc4 = (const uint4*)wcat;
#define STAGE_LOAD(cidx) { const uint4* s4 = wc4 + (cidx)*1024; \
    nx0 = s4[tid]; nx1 = s4[256 + tid]; nx2 = s4[512 + tid]; nx3 = s4[768 + tid]; }
#define STAGE_WRITE(cidx) { char* d = smem + (((cidx)&1) << 14); \
    *(uint4*)(d + tid*16) = nx0; *(uint4*)(d + (256 + tid)*16) = nx1; \
    *(uint4*)(d + (512 + tid)*16) = nx2; *(uint4*)(d + (768 + tid)*16) = nx3; }

    // prologue
    STAGE_LOAD(0); STAGE_WRITE(0); STAGE_LOAD(1);
    __syncthreads();

    f32x4 acc[2][8];
    #pragma unroll
    for (int mt = 0; mt < 2; ++mt)
        #pragma unroll
        for (int nt = 0; nt < 8; ++nt) acc[mt][nt] = (f32x4){0.f,0.f,0.f,0.f};

    // ---- phases 0,1: out-proj, K split in two halves ----
    #pragma unroll
    for (int ph = 0; ph < 2; ++ph) {
        STAGE_WRITE(ph + 1); STAGE_LOAD(ph + 2);
        short8 cfp[2][2];
        #pragma unroll
        for (int mt = 0; mt < 2; ++mt)
            #pragma unroll
            for (int j = 0; j < 2; ++j)
                cfp[mt][j] = *(const short8*)(ctx + (size_t)rc[mt]*128 + (ph*2 + j)*32 + l4*8);
        char* cur = smem + ((ph & 1) << 14);
        #pragma unroll
        for (int nt = 0; nt < 8; ++nt) {
            #pragma unroll
            for (int j = 0; j < 2; ++j) {
                int slot = (j*4 + l4) ^ (l16 & 7);
                short8 wf = *(const short8*)(cur + (nt*16 + l16)*128 + slot*16);
                acc[0][nt] = __builtin_amdgcn_mfma_f32_16x16x32_bf16(wf, cfp[0][j], acc[0][nt], 0, 0, 0);
                acc[1][nt] = __builtin_amdgcn_mfma_f32_16x16x32_bf16(wf, cfp[1][j], acc[1][nt], 0, 0, 0);
            }
        }
        __syncthreads();
    }

    // ---- bias + residual + LN1 -> yfrag ----
    float sum0 = 0.f, sq0 = 0.f, sum1 = 0.f, sq1 = 0.f;
    #pragma unroll
    for (int nt = 0; nt < 8; ++nt) {
        f32x4 obv = *(const f32x4*)(ob + nt*16 + l4*4);
        uint2 xr0 = *(const uint2*)(xb + (size_t)rc[0]*128 + nt*16 + l4*4);
        uint2 xr1 = *(const uint2*)(xb + (size_t)rc[1]*128 + nt*16 + l4*4);
        acc[0][nt][0] += obv[0] + bflo(xr0.x);
        acc[0][nt][1] += obv[1] + bfhi(xr0.x);
        acc[0][nt][2] += obv[2] + bflo(xr0.y);
        acc[0][nt][3] += obv[3] + bfhi(xr0.y);
        acc[1][nt][0] += obv[0] + bflo(xr1.x);
        acc[1][nt][1] += obv[1] + bfhi(xr1.x);
        acc[1][nt][2] += obv[2] + bflo(xr1.y);
        acc[1][nt][3] += obv[3] + bfhi(xr1.y);
        #pragma unroll
        for (int r = 0; r < 4; ++r) {
            sum0 += acc[0][nt][r]; sq0 += acc[0][nt][r]*acc[0][nt][r];
            sum1 += acc[1][nt][r]; sq1 += acc[1][nt][r]*acc[1][nt][r];
        }
    }
    sum0 += __shfl_xor(sum0, 16); sum0 += __shfl_xor(sum0, 32);
    sq0  += __shfl_xor(sq0, 16);  sq0  += __shfl_xor(sq0, 32);
    sum1 += __shfl_xor(sum1, 16); sum1 += __shfl_xor(sum1, 32);
    sq1  += __shfl_xor(sq1, 16);  sq1  += __shfl_xor(sq1, 32);
    float mean[2], rstd[2];
    mean[0] = sum0 * (1.f/128.f);
    rstd[0] = rsqrtf(sq0*(1.f/128.f) - mean[0]*mean[0] + EPS);
    mean[1] = sum1 * (1.f/128.f);
    rstd[1] = rsqrtf(sq1*(1.f/128.f) - mean[1]*mean[1] + EPS);

    short8 yfrag[2][4];
    #pragma unroll
    for (int nt = 0; nt < 8; ++nt) {
        f32x4 gv = *(const f32x4*)(g1 + nt*16 + l4*4);
        f32x4 bv = *(const f32x4*)(be1 + nt*16 + l4*4);
        #pragma unroll
        for (int mt = 0; mt < 2; ++mt)
            #pragma unroll
            for (int r = 0; r < 4; ++r) {
                float yn = (acc[mt][nt][r] - mean[mt]) * rstd[mt] * gv[r] + bv[r];
                yfrag[mt][nt >> 1][(nt & 1)*4 + r] = (short)f2bf(yn);
            }
    }

    // ---- FFN: phases 2..17 (kb = p-2), acc reused as acc2 ----
    f32x4 (&acc2)[2][8] = acc;
    #pragma unroll
    for (int mt = 0; mt < 2; ++mt)
        #pragma unroll
        for (int nt = 0; nt < 8; ++nt) acc2[mt][nt] = (f32x4){0.f,0.f,0.f,0.f};

    #pragma unroll 2
    for (int p = 2; p < 18; ++p) {
        if (p <= 16) { STAGE_WRITE(p + 1); }
        if (p <= 15) { STAGE_LOAD(p + 2); }
        const int kb = p - 2;
        char* cur = smem + ((p & 1) << 14);
        short8 wA[4], wB[4];
        #pragma unroll
        for (int c = 0; c < 4; ++c) {
            int slot = (c*4 + l4) ^ (l16 & 7);
            wA[c] = *(const short8*)(cur + l16*256 + slot*16);
            wB[c] = *(const short8*)(cur + 4096 + l16*256 + slot*16);
        }
        f32x4 hA[2] = {{0.f,0.f,0.f,0.f},{0.f,0.f,0.f,0.f}};
        f32x4 hB[2] = {{0.f,0.f,0.f,0.f},{0.f,0.f,0.f,0.f}};
        #pragma unroll
        for (int c = 0; c < 4; ++c)
            #pragma unroll
            for (int mt = 0; mt < 2; ++mt) {
                hA[mt] = __builtin_amdgcn_mfma_f32_16x16x32_bf16(wA[c], yfrag[mt][c], hA[mt], 0, 0, 0);
                hB[mt] = __builtin_amdgcn_mfma_f32_16x16x32_bf16(wB[c], yfrag[mt][c], hB[mt], 0, 0, 0);
            }
        f32x4 bA = *(const f32x4*)(b1 + kb*32 + l4*4);
        f32x4 bB = *(const f32x4*)(b1 + kb*32 + 16 + l4*4);
        short8 hf[2];
        #pragma unroll
        for (int mt = 0; mt < 2; ++mt)
            #pragma unroll
            for (int r = 0; r < 4; ++r) {
                float vA = hA[mt][r] + bA[r]; vA = vA > 0.f ? vA : 0.f;
                float vB = hB[mt][r] + bB[r]; vB = vB > 0.f ? vB : 0.f;
                hf[mt][r]     = (short)f2bf(vA);
                hf[mt][4 + r] = (short)f2bf(vB);
            }
        #pragma unroll
        for (int nt = 0; nt < 8; ++nt) {
            short8 w2f = *(const short8*)(cur + 8192 + l4*2048 + (nt*16 + l16)*16);
            acc2[0][nt] = __builtin_amdgcn_mfma_f32_16x16x32_bf16(w2f, hf[0], acc2[0][nt], 0, 0, 0);
            acc2[1][nt] = __builtin_amdgcn_mfma_f32_16x16x32_bf16(w2f, hf[1], acc2[1][nt], 0, 0, 0);
        }
        if (p < 17) __syncthreads();
    }

    // ---- s = y + ff + b2, LN2, coalesced float4 out ----
    #pragma unroll
    for (int mt = 0; mt < 2; ++mt) {
        float sum2 = 0.f, sq2 = 0.f;
        #pragma unroll
        for (int nt = 0; nt < 8; ++nt) {
            f32x4 b2v = *(const f32x4*)(b2 + nt*16 + l4*4);
            #pragma unroll
            for (int r = 0; r < 4; ++r) {
                float s = bf2f((ushort)yfrag[mt][nt >> 1][(nt & 1)*4 + r]) + acc2[mt][nt][r] + b2v[r];
                acc2[mt][nt][r] = s; sum2 += s; sq2 += s*s;
            }
        }
        sum2 += __shfl_xor(sum2, 16); sum2 += __shfl_xor(sum2, 32);
        sq2  += __shfl_xor(sq2, 16);  sq2  += __shfl_xor(sq2, 32);
        float mean2 = sum2 * (1.f/128.f);
        float rstd2 = rsqrtf(sq2*(1.f/128.f) - mean2*mean2 + EPS);
        if (row[mt] < N) {
            #pragma unroll
            for (int nt = 0; nt < 8; ++nt) {
                f32x4 gv = *(const f32x4*)(g2 + nt*16 + l4*4);
                f32x4 bv = *(const f32x4*)(be2 + nt*16 + l4*4);
                f32x4 o;
                #pragma unroll
                for (int r = 0; r < 4; ++r)
                    o[r] = (acc2[mt][nt][r] - mean2) * rstd2 * gv[r] + bv[r];
                *(f32x4*)(out + (size_t)row[mt]*128 + nt*16 + l4*4) = o;
            }
        }
    }
#undef STAGE_LOAD
#undef STAGE_WRITE
}

extern "C" void kernel_launch(void* const* d_in, const int* in_sizes, int n_in,
                              void* d_out, int out_size, void* d_ws, size_t ws_size,
                              hipStream_t stream) {
    (void)n_in; (void)out_size; (void)ws_size;
    const float* x   = (const float*)d_in[0];
    const int*   smp = (const int*)  d_in[1];
    const float* ipw = (const float*)d_in[2];
    const float* ipb = (const float*)d_in[3];
    const float* ow  = (const float*)d_in[4];
    const float* ob  = (const float*)d_in[5];
    const float* w1  = (const float*)d_in[6];
    const float* b1  = (const float*)d_in[7];
    const float* w2  = (const float*)d_in[8];
    const float* b2  = (const float*)d_in[9];
    const float* g1  = (const float*)d_in[10];
    const float* be1 = (const float*)d_in[11];
    const float* g2  = (const float*)d_in[12];
    const float* be2 = (const float*)d_in[13];
    const int N = in_sizes[0] / 128;

    ushort* qt   = (ushort*)d_ws;                   // [N][128] bf16 q, then ctx
    unsigned char* kv8 = (unsigned char*)(qt + (size_t)N*128);  // [N][256] fp8 K|V
    ushort* wqb  = (ushort*)(kv8 + (size_t)N*256);  // 384*128 natural bf16
    ushort* wcat = wqb + 384*128;                   // 18*8192 chunk stream
    ushort* xb   = wcat + 18*8192;                  // [N][128] bf16 x
    float*  outp = (float*)d_out;

    k_prep <<<576,         256, 0, stream>>>(ipw, ow, w1, w2, wqb, wcat);
    k_qkv  <<<(N+63)/64,   256, 0, stream>>>(x, wqb, ipb, qt, kv8, xb, N);
    k_attn <<<(N+3)/4,     256, 0, stream>>>(qt, kv8, smp, N);
    k_tail <<<(N+127)/128, 256, 0, stream>>>(qt, ob, xb, g1, be1,
                                             wcat, b1, b2, g2, be2, outp, N);
}

// Round 11
// 212.892 us; speedup vs baseline: 1.5743x; 1.1107x over previous
//
#include <hip/hip_runtime.h>
#include <hip/hip_bf16.h>

typedef __attribute__((ext_vector_type(8))) short short8;
typedef __attribute__((ext_vector_type(4))) float f32x4;
typedef __attribute__((ext_vector_type(2))) float f32x2;

#define EPS 1e-5f

__device__ __forceinline__ unsigned short f2bf(float f) {
    union { float f; unsigned u; } v; v.f = f;
    unsigned u = v.u;
    u += 0x7FFFu + ((u >> 16) & 1u);   // RNE
    return (unsigned short)(u >> 16);
}
__device__ __forceinline__ float bflo(unsigned u) {
    union { unsigned u; float f; } v; v.u = u << 16; return v.f;
}
__device__ __forceinline__ float bfhi(unsigned u) {
    union { unsigned u; float f; } v; v.u = u & 0xffff0000u; return v.f;
}
__device__ __forceinline__ float bf2f(ushort u) {
    union { unsigned u; float f; } v; v.u = ((unsigned)u) << 16; return v.f;
}
__device__ __forceinline__ unsigned char f2fp8(float v) {
    return (unsigned char)(__builtin_amdgcn_cvt_pk_fp8_f32(v, v, 0, false) & 0xff);
}
__device__ __forceinline__ unsigned pk4fp8(float a, float b, float c, float d) {
    unsigned u = __builtin_amdgcn_cvt_pk_fp8_f32(a, b, 0, false);
    u = __builtin_amdgcn_cvt_pk_fp8_f32(c, d, u, true);
    return u;
}
__device__ __forceinline__ int sig(int p) {            // sigma: acc-layout k-permutation
    return (((p >> 2) & 1) << 4) | (((p >> 3) & 3) << 2) | (p & 3);
}

// load 8 consecutive f32, convert to a bf16x8 MFMA fragment
__device__ __forceinline__ short8 load_frag_f32(const float* __restrict__ p) {
    f32x4 a = *(const f32x4*)p;
    f32x4 b = *(const f32x4*)(p + 4);
    short8 r;
    r[0] = (short)f2bf(a[0]); r[1] = (short)f2bf(a[1]);
    r[2] = (short)f2bf(a[2]); r[3] = (short)f2bf(a[3]);
    r[4] = (short)f2bf(b[0]); r[5] = (short)f2bf(b[1]);
    r[6] = (short)f2bf(b[2]); r[7] = (short)f2bf(b[3]);
    return r;
}

// dot(q[0..16) bf16, k[0..16) fp8) for one head
__device__ __forceinline__ float dot16_q_k8(const ushort* q, const unsigned char* kp) {
    uint4 kw = *(const uint4*)kp;
    const unsigned* qd = (const unsigned*)q;
    f32x2 a, b; float s = 0.f;
    a = __builtin_amdgcn_cvt_pk_f32_fp8(kw.x, false);
    b = __builtin_amdgcn_cvt_pk_f32_fp8(kw.x, true);
    s += a[0]*bflo(qd[0]) + a[1]*bfhi(qd[0]) + b[0]*bflo(qd[1]) + b[1]*bfhi(qd[1]);
    a = __builtin_amdgcn_cvt_pk_f32_fp8(kw.y, false);
    b = __builtin_amdgcn_cvt_pk_f32_fp8(kw.y, true);
    s += a[0]*bflo(qd[2]) + a[1]*bfhi(qd[2]) + b[0]*bflo(qd[3]) + b[1]*bfhi(qd[3]);
    a = __builtin_amdgcn_cvt_pk_f32_fp8(kw.z, false);
    b = __builtin_amdgcn_cvt_pk_f32_fp8(kw.z, true);
    s += a[0]*bflo(qd[4]) + a[1]*bfhi(qd[4]) + b[0]*bflo(qd[5]) + b[1]*bfhi(qd[5]);
    a = __builtin_amdgcn_cvt_pk_f32_fp8(kw.w, false);
    b = __builtin_amdgcn_cvt_pk_f32_fp8(kw.w, true);
    s += a[0]*bflo(qd[6]) + a[1]*bfhi(qd[6]) + b[0]*bflo(qd[7]) + b[1]*bfhi(qd[7]);
    return s;
}

// ---------------- K0: weight transforms -------------------------------------
// wqb: bf16 copy of in_proj_w (for k_qkv).
// wcat8: 144KB fp8(e4m3, x16-scaled) LDS image for k_tail:
//   [0,16K):    wob8  [128 rows][16 slots of 8B], slot ^= (row&15)
//   [16K,80K):  w1s8  16 kb x [32 rows][16 slots], slot-xor (row&15) + sigma cols
//   [80K,144K): w2s8  16 kb x [4 chunks][128 rows][8B], sigma on hidden
__global__ __launch_bounds__(256) void k_prep(
        const float* __restrict__ ipw, const float* __restrict__ ow,
        const float* __restrict__ w1, const float* __restrict__ w2,
        ushort* __restrict__ wqb, unsigned char* __restrict__ wcat8) {
    int i = blockIdx.x * 256 + threadIdx.x;
    if (i < 49152) wqb[i] = f2bf(ipw[i]);
    if (i < 147456) {
        float v;
        if (i < 16384) {
            int r = i >> 7, s = (i >> 3) & 15, e = i & 7;
            v = ow[r*128 + ((s ^ (r & 15)) << 3) + e];
        } else if (i < 81920) {
            int j = i - 16384;
            int kb = j >> 12, r = (j >> 7) & 31, s = (j >> 3) & 15, e = j & 7;
            int cp = ((s ^ (r & 15)) << 3) + e;
            int cs = (cp & ~31) | sig(cp & 31);
            v = w1[(kb*32 + r)*128 + cs];
        } else {
            int j = i - 81920;
            int kb = j >> 12, ch = (j >> 10) & 3, rw = (j >> 3) & 127, e = j & 7;
            v = w2[rw*512 + kb*32 + sig(ch*8 + e)];
        }
        wcat8[i] = f2fp8(16.f * v);
    }
}

// ---------------- K1: qkv projection, LDS-transposed coalesced stores -------
__global__ __launch_bounds__(256) void k_qkv(
        const float* __restrict__ x, const ushort* __restrict__ w,
        const float* __restrict__ bias, ushort* __restrict__ qt,
        unsigned char* __restrict__ kv8, ushort* __restrict__ xb, int N) {
    __shared__ ushort sls[64 * 392];
    const int wave = threadIdx.x >> 6, lane = threadIdx.x & 63;
    const int l16 = lane & 15, l4 = lane >> 4;
    const int base = blockIdx.x * 64;

    short8 af[4][4];
    #pragma unroll
    for (int mt = 0; mt < 4; ++mt) {
        int row = base + mt*16 + l16;
        int rc = row < N ? row : N - 1;
        const float* p = x + (size_t)rc*128 + l4*8;
        #pragma unroll
        for (int kb = 0; kb < 4; ++kb) af[mt][kb] = load_frag_f32(p + kb*32);
    }
    #pragma unroll
    for (int mt = 0; mt < 4; ++mt) {
        int row = base + mt*16 + l16;
        if (row < N) {
            #pragma unroll
            for (int kb = 0; kb < 4; ++kb)
                *(short8*)(xb + (size_t)row*128 + kb*32 + l4*8) = af[mt][kb];
        }
    }
    #pragma unroll
    for (int i = 0; i < 6; ++i) {
        int col = (wave*6 + i)*16 + l16;
        const ushort* pw = w + (size_t)col*128 + l4*8;
        short8 bf[4];
        #pragma unroll
        for (int kb = 0; kb < 4; ++kb) bf[kb] = *(const short8*)(pw + kb*32);
        float bv = bias[col];
        #pragma unroll
        for (int mt = 0; mt < 4; ++mt) {
            f32x4 acc = {0.f, 0.f, 0.f, 0.f};
            #pragma unroll
            for (int kb = 0; kb < 4; ++kb)
                acc = __builtin_amdgcn_mfma_f32_16x16x32_bf16(af[mt][kb], bf[kb], acc, 0, 0, 0);
            #pragma unroll
            for (int r = 0; r < 4; ++r)
                sls[(mt*16 + l4*4 + r)*392 + col] = f2bf(acc[r] + bv);
        }
    }
    __syncthreads();
    // coalesced epilogue: row = tid>>2, quarter q = tid&3
    {
        const int row = threadIdx.x >> 2, q = threadIdx.x & 3;
        const int grow = base + row;
        if (grow < N) {
            const ushort* sp = sls + row*392;
            // qt: 32 bf16 (cols q*32..)
            #pragma unroll
            for (int j = 0; j < 4; ++j) {
                uint4 v = *(const uint4*)(sp + q*32 + j*8);
                *(uint4*)(qt + (size_t)grow*128 + q*32 + j*8) = v;
            }
            // kv8: 64 fp8 (cols 128 + q*64..)
            #pragma unroll
            for (int j = 0; j < 4; ++j) {
                unsigned wds[4];
                #pragma unroll
                for (int h = 0; h < 4; ++h) {
                    const ushort* e = sp + 128 + q*64 + j*16 + h*4;
                    wds[h] = pk4fp8(bf2f(e[0]), bf2f(e[1]), bf2f(e[2]), bf2f(e[3]));
                }
                *(uint4*)(kv8 + (size_t)grow*256 + q*64 + j*16) =
                    make_uint4(wds[0], wds[1], wds[2], wds[3]);
            }
        }
    }
}

// ---------------- K2: sampled attention, fp8 K/V gather ---------------------
// ctx written as fp8 (x8 scale) into first 128B of the dead q row.
__global__ __launch_bounds__(256) void k_attn(
        ushort* __restrict__ qt, const unsigned char* __restrict__ kv8,
        const int* __restrict__ samp, int N) {
    __shared__ float aw[4][8][17];
    __shared__ int   ai[4][16];
    const int wave = threadIdx.x >> 6, lane = threadIdx.x & 63;
    const int n = blockIdx.x * 4 + wave;
    if (n >= N) return;
    const int k  = lane & 15;
    const int hp = lane >> 4;
    const int h0 = hp, h1 = hp + 4;

    const int idx = samp[(size_t)n*16 + k];
    const ushort* qrow = qt + (size_t)n*128;
    const unsigned char* krow = kv8 + (size_t)idx*256;

    float s0 = dot16_q_k8(qrow + h0*16, krow + h0*16);
    float s1 = dot16_q_k8(qrow + h1*16, krow + h1*16);
    s0 *= 0.25f; s1 *= 0.25f;
    float m0 = s0, m1 = s1;
    #pragma unroll
    for (int off = 1; off < 16; off <<= 1) {
        m0 = fmaxf(m0, __shfl_xor(m0, off));
        m1 = fmaxf(m1, __shfl_xor(m1, off));
    }
    float e0 = __expf(s0 - m0), e1 = __expf(s1 - m1);
    float d0 = e0, d1 = e1;
    #pragma unroll
    for (int off = 1; off < 16; off <<= 1) {
        d0 += __shfl_xor(d0, off);
        d1 += __shfl_xor(d1, off);
    }
    aw[wave][h0][k] = e0 / d0;
    aw[wave][h1][k] = e1 / d1;
    if (hp == 0) ai[wave][k] = idx;

    const int c = lane & 15;
    const int g = lane >> 4;
    const int h = c >> 1;

    int rows[4];
    #pragma unroll
    for (int b = 0; b < 4; ++b) rows[b] = ai[wave][g + b*4];
    uint2 vv[4];
    #pragma unroll
    for (int b = 0; b < 4; ++b)
        vv[b] = *(const uint2*)(kv8 + (size_t)(unsigned)rows[b]*256 + 128 + c*8);
    float wk[4];
    #pragma unroll
    for (int b = 0; b < 4; ++b) wk[b] = aw[wave][h][g + b*4];

    float a8[8] = {0.f,0.f,0.f,0.f,0.f,0.f,0.f,0.f};
    #pragma unroll
    for (int b = 0; b < 4; ++b) {
        f32x2 p;
        p = __builtin_amdgcn_cvt_pk_f32_fp8(vv[b].x, false);
        a8[0] = fmaf(wk[b], p[0], a8[0]); a8[1] = fmaf(wk[b], p[1], a8[1]);
        p = __builtin_amdgcn_cvt_pk_f32_fp8(vv[b].x, true);
        a8[2] = fmaf(wk[b], p[0], a8[2]); a8[3] = fmaf(wk[b], p[1], a8[3]);
        p = __builtin_amdgcn_cvt_pk_f32_fp8(vv[b].y, false);
        a8[4] = fmaf(wk[b], p[0], a8[4]); a8[5] = fmaf(wk[b], p[1], a8[5]);
        p = __builtin_amdgcn_cvt_pk_f32_fp8(vv[b].y, true);
        a8[6] = fmaf(wk[b], p[0], a8[6]); a8[7] = fmaf(wk[b], p[1], a8[7]);
    }
    #pragma unroll
    for (int i = 0; i < 8; ++i) {
        a8[i] += __shfl_xor(a8[i], 16);
        a8[i] += __shfl_xor(a8[i], 32);
    }
    if (lane < 16) {
        unsigned lo = pk4fp8(8.f*a8[0], 8.f*a8[1], 8.f*a8[2], 8.f*a8[3]);
        unsigned hi = pk4fp8(8.f*a8[4], 8.f*a8[5], 8.f*a8[6], 8.f*a8[7]);
        *(uint2*)((unsigned char*)qt + (size_t)n*256 + c*8) = make_uint2(lo, hi);
    }
}

// ---------------- K3: fused tail — ALL weights resident in 144KB LDS --------
// 512 threads (8 waves), 1 block/CU, grid=256 persistent blocks.
// Load weights once (one barrier), then each wave independently grid-strides
// over 32-row tiles: zero __syncthreads, zero weight re-streaming.
// fp8 MFMA (16x16x32_fp8_fp8): same C/D layout as bf16 -> sigma algebra kept.
// Scales: weights x16, ctx x8 -> oproj acc/128; w1 acc/16; w2 acc/16.
__global__ __launch_bounds__(512) void k_tail(
        const unsigned char* __restrict__ ctx8, const float* __restrict__ ob,
        const ushort* __restrict__ xb,
        const float* __restrict__ g1, const float* __restrict__ be1,
        const unsigned char* __restrict__ wcat8, const float* __restrict__ b1,
        const float* __restrict__ b2,
        const float* __restrict__ g2, const float* __restrict__ be2,
        float* __restrict__ out, int N) {
    __shared__ __align__(16) unsigned char smem[147456];
    const int tid = threadIdx.x;
    const int wave = tid >> 6, lane = tid & 63;
    const int l16 = lane & 15, l4 = lane >> 4;

    // one-time weight load: 147456B / 512thr = 18 x uint4 per thread
    {
        const uint4* src = (const uint4*)wcat8;
        #pragma unroll
        for (int b = 0; b < 3; ++b) {
            uint4 v[6];
            #pragma unroll
            for (int j = 0; j < 6; ++j) v[j] = src[(b*6 + j)*512 + tid];
            #pragma unroll
            for (int j = 0; j < 6; ++j)
                *(uint4*)(smem + ((size_t)(b*6 + j)*512 + tid)*16) = v[j];
        }
    }
    __syncthreads();

    const int ntiles = (N + 31) >> 5;
    const int nwv = gridDim.x * 8;
    for (int t = blockIdx.x * 8 + wave; t < ntiles; t += nwv) {
        int row[2], rc[2];
        row[0] = t*32 + l16;      rc[0] = row[0] < N ? row[0] : N - 1;
        row[1] = t*32 + 16 + l16; rc[1] = row[1] < N ? row[1] : N - 1;

        // ---- out-proj: A = wob8 (LDS), B = ctx8 (global fp8) ----
        long cf[2][4];
        #pragma unroll
        for (int mt = 0; mt < 2; ++mt)
            #pragma unroll
            for (int c = 0; c < 4; ++c)
                cf[mt][c] = *(const long*)(ctx8 + (size_t)rc[mt]*256 + c*32 + l4*8);
        f32x4 acc[2][8];
        #pragma unroll
        for (int mt = 0; mt < 2; ++mt)
            #pragma unroll
            for (int nt = 0; nt < 8; ++nt) acc[mt][nt] = (f32x4){0.f,0.f,0.f,0.f};
        #pragma unroll
        for (int nt = 0; nt < 8; ++nt) {
            #pragma unroll
            for (int c = 0; c < 4; ++c) {
                long wf = *(const long*)(smem + (nt*16 + l16)*128 + (((c*4 + l4) ^ l16) << 3));
                acc[0][nt] = __builtin_amdgcn_mfma_f32_16x16x32_fp8_fp8(wf, cf[0][c], acc[0][nt], 0, 0, 0);
                acc[1][nt] = __builtin_amdgcn_mfma_f32_16x16x32_fp8_fp8(wf, cf[1][c], acc[1][nt], 0, 0, 0);
            }
        }

        // ---- bias + x residual + LN1 ----
        float sum0 = 0.f, sq0 = 0.f, sum1 = 0.f, sq1 = 0.f;
        #pragma unroll
        for (int nt = 0; nt < 8; ++nt) {
            f32x4 obv = *(const f32x4*)(ob + nt*16 + l4*4);
            uint2 xr0 = *(const uint2*)(xb + (size_t)rc[0]*128 + nt*16 + l4*4);
            uint2 xr1 = *(const uint2*)(xb + (size_t)rc[1]*128 + nt*16 + l4*4);
            acc[0][nt][0] = acc[0][nt][0]*(1.f/128.f) + obv[0] + bflo(xr0.x);
            acc[0][nt][1] = acc[0][nt][1]*(1.f/128.f) + obv[1] + bfhi(xr0.x);
            acc[0][nt][2] = acc[0][nt][2]*(1.f/128.f) + obv[2] + bflo(xr0.y);
            acc[0][nt][3] = acc[0][nt][3]*(1.f/128.f) + obv[3] + bfhi(xr0.y);
            acc[1][nt][0] = acc[1][nt][0]*(1.f/128.f) + obv[0] + bflo(xr1.x);
            acc[1][nt][1] = acc[1][nt][1]*(1.f/128.f) + obv[1] + bfhi(xr1.x);
            acc[1][nt][2] = acc[1][nt][2]*(1.f/128.f) + obv[2] + bflo(xr1.y);
            acc[1][nt][3] = acc[1][nt][3]*(1.f/128.f) + obv[3] + bfhi(xr1.y);
            #pragma unroll
            for (int r = 0; r < 4; ++r) {
                sum0 += acc[0][nt][r]; sq0 += acc[0][nt][r]*acc[0][nt][r];
                sum1 += acc[1][nt][r]; sq1 += acc[1][nt][r]*acc[1][nt][r];
            }
        }
        sum0 += __shfl_xor(sum0, 16); sum0 += __shfl_xor(sum0, 32);
        sq0  += __shfl_xor(sq0, 16);  sq0  += __shfl_xor(sq0, 32);
        sum1 += __shfl_xor(sum1, 16); sum1 += __shfl_xor(sum1, 32);
        sq1  += __shfl_xor(sq1, 16);  sq1  += __shfl_xor(sq1, 32);
        float mean[2], rstd[2];
        mean[0] = sum0 * (1.f/128.f);
        rstd[0] = rsqrtf(sq0*(1.f/128.f) - mean[0]*mean[0] + EPS);
        mean[1] = sum1 * (1.f/128.f);
        rstd[1] = rsqrtf(sq1*(1.f/128.f) - mean[1]*mean[1] + EPS);

        // y -> bf16 (residual) + fp8 (MFMA B-operand)
        short8 yf16[2][4];
        long   yf8[2][4];
        #pragma unroll
        for (int mt = 0; mt < 2; ++mt) {
            #pragma unroll
            for (int c = 0; c < 4; ++c) {
                float yv[8];
                #pragma unroll
                for (int half = 0; half < 2; ++half) {
                    int nt = 2*c + half;
                    f32x4 gv = *(const f32x4*)(g1 + nt*16 + l4*4);
                    f32x4 bv = *(const f32x4*)(be1 + nt*16 + l4*4);
                    #pragma unroll
                    for (int r = 0; r < 4; ++r) {
                        float yn = (acc[mt][nt][r] - mean[mt]) * rstd[mt] * gv[r] + bv[r];
                        yv[half*4 + r] = yn;
                        yf16[mt][c][half*4 + r] = (short)f2bf(yn);
                    }
                }
                unsigned lo = pk4fp8(yv[0], yv[1], yv[2], yv[3]);
                unsigned hi = pk4fp8(yv[4], yv[5], yv[6], yv[7]);
                yf8[mt][c] = (long)(((unsigned long long)hi << 32) | lo);
            }
        }

        // ---- FFN: all weights in LDS, no barriers ----
        f32x4 acc2[2][8];
        #pragma unroll
        for (int mt = 0; mt < 2; ++mt)
            #pragma unroll
            for (int nt = 0; nt < 8; ++nt) acc2[mt][nt] = (f32x4){0.f,0.f,0.f,0.f};
        #pragma unroll 4
        for (int kb = 0; kb < 16; ++kb) {
            const unsigned char* w1b = smem + 16384 + kb*4096;
            long wA[4], wB[4];
            #pragma unroll
            for (int c = 0; c < 4; ++c) {
                int so = ((c*4 + l4) ^ l16) << 3;
                wA[c] = *(const long*)(w1b + l16*128 + so);
                wB[c] = *(const long*)(w1b + (16 + l16)*128 + so);
            }
            f32x4 hA[2] = {{0.f,0.f,0.f,0.f},{0.f,0.f,0.f,0.f}};
            f32x4 hB[2] = {{0.f,0.f,0.f,0.f},{0.f,0.f,0.f,0.f}};
            #pragma unroll
            for (int c = 0; c < 4; ++c)
                #pragma unroll
                for (int mt = 0; mt < 2; ++mt) {
                    hA[mt] = __builtin_amdgcn_mfma_f32_16x16x32_fp8_fp8(wA[c], yf8[mt][c], hA[mt], 0, 0, 0);
                    hB[mt] = __builtin_amdgcn_mfma_f32_16x16x32_fp8_fp8(wB[c], yf8[mt][c], hB[mt], 0, 0, 0);
                }
            f32x4 bA = *(const f32x4*)(b1 + kb*32 + l4*4);
            f32x4 bB = *(const f32x4*)(b1 + kb*32 + 16 + l4*4);
            long hf8[2];
            #pragma unroll
            for (int mt = 0; mt < 2; ++mt) {
                float vA[4], vB[4];
                #pragma unroll
                for (int r = 0; r < 4; ++r) {
                    vA[r] = fmaxf(hA[mt][r]*0.0625f + bA[r], 0.f);
                    vB[r] = fmaxf(hB[mt][r]*0.0625f + bB[r], 0.f);
                }
                unsigned lo = pk4fp8(vA[0], vA[1], vA[2], vA[3]);
                unsigned hi = pk4fp8(vB[0], vB[1], vB[2], vB[3]);
                hf8[mt] = (long)(((unsigned long long)hi << 32) | lo);
            }
            const unsigned char* w2b = smem + 81920 + kb*4096 + l4*1024;
            #pragma unroll
            for (int nt = 0; nt < 8; ++nt) {
                long w2f = *(const long*)(w2b + (nt*16 + l16)*8);
                acc2[0][nt] = __builtin_amdgcn_mfma_f32_16x16x32_fp8_fp8(w2f, hf8[0], acc2[0][nt], 0, 0, 0);
                acc2[1][nt] = __builtin_amdgcn_mfma_f32_16x16x32_fp8_fp8(w2f, hf8[1], acc2[1][nt], 0, 0, 0);
            }
        }

        // ---- s = y + ff/16 + b2, LN2, store ----
        #pragma unroll
        for (int mt = 0; mt < 2; ++mt) {
            float sum2 = 0.f, sq2 = 0.f;
            #pragma unroll
            for (int nt = 0; nt < 8; ++nt) {
                f32x4 b2v = *(const f32x4*)(b2 + nt*16 + l4*4);
                #pragma unroll
                for (int r = 0; r < 4; ++r) {
                    float s = bf2f((ushort)yf16[mt][nt >> 1][(nt & 1)*4 + r])
                              + acc2[mt][nt][r]*0.0625f + b2v[r];
                    acc2[mt][nt][r] = s; sum2 += s; sq2 += s*s;
                }
            }
            sum2 += __shfl_xor(sum2, 16); sum2 += __shfl_xor(sum2, 32);
            sq2  += __shfl_xor(sq2, 16);  sq2  += __shfl_xor(sq2, 32);
            float mean2 = sum2 * (1.f/128.f);
            float rstd2 = rsqrtf(sq2*(1.f/128.f) - mean2*mean2 + EPS);
            if (row[mt] < N) {
                #pragma unroll
                for (int nt = 0; nt < 8; ++nt) {
                    f32x4 gv = *(const f32x4*)(g2 + nt*16 + l4*4);
                    f32x4 bv = *(const f32x4*)(be2 + nt*16 + l4*4);
                    f32x4 o;
                    #pragma unroll
                    for (int r = 0; r < 4; ++r)
                        o[r] = (acc2[mt][nt][r] - mean2) * rstd2 * gv[r] + bv[r];
                    *(f32x4*)(out + (size_t)row[mt]*128 + nt*16 + l4*4) = o;
                }
            }
        }
    }
}

extern "C" void kernel_launch(void* const* d_in, const int* in_sizes, int n_in,
                              void* d_out, int out_size, void* d_ws, size_t ws_size,
                              hipStream_t stream) {
    (void)n_in; (void)out_size; (void)ws_size;
    const float* x   = (const float*)d_in[0];
    const int*   smp = (const int*)  d_in[1];
    const float* ipw = (const float*)d_in[2];
    const float* ipb = (const float*)d_in[3];
    const float* ow  = (const float*)d_in[4];
    const float* ob  = (const float*)d_in[5];
    const float* w1  = (const float*)d_in[6];
    const float* b1  = (const float*)d_in[7];
    const float* w2  = (const float*)d_in[8];
    const float* b2  = (const float*)d_in[9];
    const float* g1  = (const float*)d_in[10];
    const float* be1 = (const float*)d_in[11];
    const float* g2  = (const float*)d_in[12];
    const float* be2 = (const float*)d_in[13];
    const int N = in_sizes[0] / 128;

    ushort* qt   = (ushort*)d_ws;                        // [N][128] bf16 q; ctx8 fp8 overlays
    unsigned char* kv8 = (unsigned char*)(qt + (size_t)N*128);   // [N][256] fp8 K|V
    ushort* wqb  = (ushort*)(kv8 + (size_t)N*256);       // 384*128 bf16
    unsigned char* wcat8 = (unsigned char*)(wqb + 49152);// 147456 B fp8 LDS image
    ushort* xb   = (ushort*)(wcat8 + 147456);            // [N][128] bf16 x
    float*  outp = (float*)d_out;

    k_prep <<<576,       256, 0, stream>>>(ipw, ow, w1, w2, wqb, wcat8);
    k_qkv  <<<(N+63)/64, 256, 0, stream>>>(x, wqb, ipb, qt, kv8, xb, N);
    k_attn <<<(N+3)/4,   256, 0, stream>>>(qt, kv8, smp, N);
    k_tail <<<256,       512, 0, stream>>>((const unsigned char*)qt, ob, xb, g1, be1,
                                           wcat8, b1, b2, g2, be2, outp, N);
}

// Round 12
// 211.145 us; speedup vs baseline: 1.5873x; 1.0083x over previous
//
#include <hip/hip_runtime.h>
#include <hip/hip_bf16.h>

typedef __attribute__((ext_vector_type(8))) short short8;
typedef __attribute__((ext_vector_type(4))) float f32x4;
typedef __attribute__((ext_vector_type(2))) float f32x2;

#define EPS 1e-5f

__device__ __forceinline__ unsigned short f2bf(float f) {
    union { float f; unsigned u; } v; v.f = f;
    unsigned u = v.u;
    u += 0x7FFFu + ((u >> 16) & 1u);   // RNE
    return (unsigned short)(u >> 16);
}
__device__ __forceinline__ float bflo(unsigned u) {
    union { unsigned u; float f; } v; v.u = u << 16; return v.f;
}
__device__ __forceinline__ float bfhi(unsigned u) {
    union { unsigned u; float f; } v; v.u = u & 0xffff0000u; return v.f;
}
__device__ __forceinline__ float bf2f(ushort u) {
    union { unsigned u; float f; } v; v.u = ((unsigned)u) << 16; return v.f;
}
__device__ __forceinline__ unsigned char f2fp8(float v) {
    return (unsigned char)(__builtin_amdgcn_cvt_pk_fp8_f32(v, v, 0, false) & 0xff);
}
__device__ __forceinline__ unsigned pk4fp8(float a, float b, float c, float d) {
    unsigned u = __builtin_amdgcn_cvt_pk_fp8_f32(a, b, 0, false);
    u = __builtin_amdgcn_cvt_pk_fp8_f32(c, d, u, true);
    return u;
}
__device__ __forceinline__ int sig(int p) {            // sigma: acc-layout k-permutation
    return (((p >> 2) & 1) << 4) | (((p >> 3) & 3) << 2) | (p & 3);
}

// load 8 consecutive f32, convert to a bf16x8 MFMA fragment
__device__ __forceinline__ short8 load_frag_f32(const float* __restrict__ p) {
    f32x4 a = *(const f32x4*)p;
    f32x4 b = *(const f32x4*)(p + 4);
    short8 r;
    r[0] = (short)f2bf(a[0]); r[1] = (short)f2bf(a[1]);
    r[2] = (short)f2bf(a[2]); r[3] = (short)f2bf(a[3]);
    r[4] = (short)f2bf(b[0]); r[5] = (short)f2bf(b[1]);
    r[6] = (short)f2bf(b[2]); r[7] = (short)f2bf(b[3]);
    return r;
}

// dot(q[0..16) bf16, k[0..16) fp8) for one head
__device__ __forceinline__ float dot16_q_k8(const ushort* q, const unsigned char* kp) {
    uint4 kw = *(const uint4*)kp;
    const unsigned* qd = (const unsigned*)q;
    f32x2 a, b; float s = 0.f;
    a = __builtin_amdgcn_cvt_pk_f32_fp8(kw.x, false);
    b = __builtin_amdgcn_cvt_pk_f32_fp8(kw.x, true);
    s += a[0]*bflo(qd[0]) + a[1]*bfhi(qd[0]) + b[0]*bflo(qd[1]) + b[1]*bfhi(qd[1]);
    a = __builtin_amdgcn_cvt_pk_f32_fp8(kw.y, false);
    b = __builtin_amdgcn_cvt_pk_f32_fp8(kw.y, true);
    s += a[0]*bflo(qd[2]) + a[1]*bfhi(qd[2]) + b[0]*bflo(qd[3]) + b[1]*bfhi(qd[3]);
    a = __builtin_amdgcn_cvt_pk_f32_fp8(kw.z, false);
    b = __builtin_amdgcn_cvt_pk_f32_fp8(kw.z, true);
    s += a[0]*bflo(qd[4]) + a[1]*bfhi(qd[4]) + b[0]*bflo(qd[5]) + b[1]*bfhi(qd[5]);
    a = __builtin_amdgcn_cvt_pk_f32_fp8(kw.w, false);
    b = __builtin_amdgcn_cvt_pk_f32_fp8(kw.w, true);
    s += a[0]*bflo(qd[6]) + a[1]*bfhi(qd[6]) + b[0]*bflo(qd[7]) + b[1]*bfhi(qd[7]);
    return s;
}

// ---------------- K0: weight transforms (unchanged from R11) ----------------
__global__ __launch_bounds__(256) void k_prep(
        const float* __restrict__ ipw, const float* __restrict__ ow,
        const float* __restrict__ w1, const float* __restrict__ w2,
        ushort* __restrict__ wqb, unsigned char* __restrict__ wcat8) {
    int i = blockIdx.x * 256 + threadIdx.x;
    if (i < 49152) wqb[i] = f2bf(ipw[i]);
    if (i < 147456) {
        float v;
        if (i < 16384) {
            int r = i >> 7, s = (i >> 3) & 15, e = i & 7;
            v = ow[r*128 + ((s ^ (r & 15)) << 3) + e];
        } else if (i < 81920) {
            int j = i - 16384;
            int kb = j >> 12, r = (j >> 7) & 31, s = (j >> 3) & 15, e = j & 7;
            int cp = ((s ^ (r & 15)) << 3) + e;
            int cs = (cp & ~31) | sig(cp & 31);
            v = w1[(kb*32 + r)*128 + cs];
        } else {
            int j = i - 81920;
            int kb = j >> 12, ch = (j >> 10) & 3, rw = (j >> 3) & 127, e = j & 7;
            v = w2[rw*512 + kb*32 + sig(ch*8 + e)];
        }
        wcat8[i] = f2fp8(16.f * v);
    }
}

// ---------------- K1: qkv projection, LDS-transposed coalesced stores -------
__global__ __launch_bounds__(256) void k_qkv(
        const float* __restrict__ x, const ushort* __restrict__ w,
        const float* __restrict__ bias, ushort* __restrict__ qt,
        unsigned char* __restrict__ kv8, ushort* __restrict__ xb, int N) {
    __shared__ ushort sls[64 * 392];
    const int wave = threadIdx.x >> 6, lane = threadIdx.x & 63;
    const int l16 = lane & 15, l4 = lane >> 4;
    const int base = blockIdx.x * 64;

    short8 af[4][4];
    #pragma unroll
    for (int mt = 0; mt < 4; ++mt) {
        int row = base + mt*16 + l16;
        int rc = row < N ? row : N - 1;
        const float* p = x + (size_t)rc*128 + l4*8;
        #pragma unroll
        for (int kb = 0; kb < 4; ++kb) af[mt][kb] = load_frag_f32(p + kb*32);
    }
    #pragma unroll
    for (int mt = 0; mt < 4; ++mt) {
        int row = base + mt*16 + l16;
        if (row < N) {
            #pragma unroll
            for (int kb = 0; kb < 4; ++kb)
                *(short8*)(xb + (size_t)row*128 + kb*32 + l4*8) = af[mt][kb];
        }
    }
    #pragma unroll
    for (int i = 0; i < 6; ++i) {
        int col = (wave*6 + i)*16 + l16;
        const ushort* pw = w + (size_t)col*128 + l4*8;
        short8 bf[4];
        #pragma unroll
        for (int kb = 0; kb < 4; ++kb) bf[kb] = *(const short8*)(pw + kb*32);
        float bv = bias[col];
        #pragma unroll
        for (int mt = 0; mt < 4; ++mt) {
            f32x4 acc = {0.f, 0.f, 0.f, 0.f};
            #pragma unroll
            for (int kb = 0; kb < 4; ++kb)
                acc = __builtin_amdgcn_mfma_f32_16x16x32_bf16(af[mt][kb], bf[kb], acc, 0, 0, 0);
            #pragma unroll
            for (int r = 0; r < 4; ++r)
                sls[(mt*16 + l4*4 + r)*392 + col] = f2bf(acc[r] + bv);
        }
    }
    __syncthreads();
    // coalesced epilogue: row = tid>>2, quarter q = tid&3
    {
        const int row = threadIdx.x >> 2, q = threadIdx.x & 3;
        const int grow = base + row;
        if (grow < N) {
            const ushort* sp = sls + row*392;
            #pragma unroll
            for (int j = 0; j < 4; ++j) {
                uint4 v = *(const uint4*)(sp + q*32 + j*8);
                *(uint4*)(qt + (size_t)grow*128 + q*32 + j*8) = v;
            }
            #pragma unroll
            for (int j = 0; j < 4; ++j) {
                unsigned wds[4];
                #pragma unroll
                for (int h = 0; h < 4; ++h) {
                    const ushort* e = sp + 128 + q*64 + j*16 + h*4;
                    wds[h] = pk4fp8(bf2f(e[0]), bf2f(e[1]), bf2f(e[2]), bf2f(e[3]));
                }
                *(uint4*)(kv8 + (size_t)grow*256 + q*64 + j*16) =
                    make_uint4(wds[0], wds[1], wds[2], wds[3]);
            }
        }
    }
}

// ---------------- K2: sampled attention, fp8 K/V gather (unchanged) ---------
__global__ __launch_bounds__(256) void k_attn(
        ushort* __restrict__ qt, const unsigned char* __restrict__ kv8,
        const int* __restrict__ samp, int N) {
    __shared__ float aw[4][8][17];
    __shared__ int   ai[4][16];
    const int wave = threadIdx.x >> 6, lane = threadIdx.x & 63;
    const int n = blockIdx.x * 4 + wave;
    if (n >= N) return;
    const int k  = lane & 15;
    const int hp = lane >> 4;
    const int h0 = hp, h1 = hp + 4;

    const int idx = samp[(size_t)n*16 + k];
    const ushort* qrow = qt + (size_t)n*128;
    const unsigned char* krow = kv8 + (size_t)idx*256;

    float s0 = dot16_q_k8(qrow + h0*16, krow + h0*16);
    float s1 = dot16_q_k8(qrow + h1*16, krow + h1*16);
    s0 *= 0.25f; s1 *= 0.25f;
    float m0 = s0, m1 = s1;
    #pragma unroll
    for (int off = 1; off < 16; off <<= 1) {
        m0 = fmaxf(m0, __shfl_xor(m0, off));
        m1 = fmaxf(m1, __shfl_xor(m1, off));
    }
    float e0 = __expf(s0 - m0), e1 = __expf(s1 - m1);
    float d0 = e0, d1 = e1;
    #pragma unroll
    for (int off = 1; off < 16; off <<= 1) {
        d0 += __shfl_xor(d0, off);
        d1 += __shfl_xor(d1, off);
    }
    aw[wave][h0][k] = e0 / d0;
    aw[wave][h1][k] = e1 / d1;
    if (hp == 0) ai[wave][k] = idx;

    const int c = lane & 15;
    const int g = lane >> 4;
    const int h = c >> 1;

    int rows[4];
    #pragma unroll
    for (int b = 0; b < 4; ++b) rows[b] = ai[wave][g + b*4];
    uint2 vv[4];
    #pragma unroll
    for (int b = 0; b < 4; ++b)
        vv[b] = *(const uint2*)(kv8 + (size_t)(unsigned)rows[b]*256 + 128 + c*8);
    float wk[4];
    #pragma unroll
    for (int b = 0; b < 4; ++b) wk[b] = aw[wave][h][g + b*4];

    float a8[8] = {0.f,0.f,0.f,0.f,0.f,0.f,0.f,0.f};
    #pragma unroll
    for (int b = 0; b < 4; ++b) {
        f32x2 p;
        p = __builtin_amdgcn_cvt_pk_f32_fp8(vv[b].x, false);
        a8[0] = fmaf(wk[b], p[0], a8[0]); a8[1] = fmaf(wk[b], p[1], a8[1]);
        p = __builtin_amdgcn_cvt_pk_f32_fp8(vv[b].x, true);
        a8[2] = fmaf(wk[b], p[0], a8[2]); a8[3] = fmaf(wk[b], p[1], a8[3]);
        p = __builtin_amdgcn_cvt_pk_f32_fp8(vv[b].y, false);
        a8[4] = fmaf(wk[b], p[0], a8[4]); a8[5] = fmaf(wk[b], p[1], a8[5]);
        p = __builtin_amdgcn_cvt_pk_f32_fp8(vv[b].y, true);
        a8[6] = fmaf(wk[b], p[0], a8[6]); a8[7] = fmaf(wk[b], p[1], a8[7]);
    }
    #pragma unroll
    for (int i = 0; i < 8; ++i) {
        a8[i] += __shfl_xor(a8[i], 16);
        a8[i] += __shfl_xor(a8[i], 32);
    }
    if (lane < 16) {
        unsigned lo = pk4fp8(8.f*a8[0], 8.f*a8[1], 8.f*a8[2], 8.f*a8[3]);
        unsigned hi = pk4fp8(8.f*a8[4], 8.f*a8[5], 8.f*a8[6], 8.f*a8[7]);
        *(uint2*)((unsigned char*)qt + (size_t)n*256 + c*8) = make_uint2(lo, hi);
    }
}

// ---------------- K3: fused tail — ALL weights resident in 144KB LDS --------
// 512 threads (8 waves), 1 block/CU (forced by LDS). launch_bounds(512,2)
// legalizes 256 VGPR (2 waves/EU is the LDS-forced occupancy anyway) — R11's
// default cap of 128 VGPR spilled ~130MB/dispatch to scratch. acc2 aliases acc.
__global__ __launch_bounds__(512, 2) void k_tail(
        const unsigned char* __restrict__ ctx8, const float* __restrict__ ob,
        const ushort* __restrict__ xb,
        const float* __restrict__ g1, const float* __restrict__ be1,
        const unsigned char* __restrict__ wcat8, const float* __restrict__ b1,
        const float* __restrict__ b2,
        const float* __restrict__ g2, const float* __restrict__ be2,
        float* __restrict__ out, int N) {
    __shared__ __align__(16) unsigned char smem[147456];
    const int tid = threadIdx.x;
    const int wave = tid >> 6, lane = tid & 63;
    const int l16 = lane & 15, l4 = lane >> 4;

    // one-time weight load: 147456B / 512thr = 18 x uint4 per thread
    {
        const uint4* src = (const uint4*)wcat8;
        #pragma unroll
        for (int b = 0; b < 3; ++b) {
            uint4 v[6];
            #pragma unroll
            for (int j = 0; j < 6; ++j) v[j] = src[(b*6 + j)*512 + tid];
            #pragma unroll
            for (int j = 0; j < 6; ++j)
                *(uint4*)(smem + ((size_t)(b*6 + j)*512 + tid)*16) = v[j];
        }
    }
    __syncthreads();

    const int ntiles = (N + 31) >> 5;
    const int nwv = gridDim.x * 8;
    for (int t = blockIdx.x * 8 + wave; t < ntiles; t += nwv) {
        int row[2], rc[2];
        row[0] = t*32 + l16;      rc[0] = row[0] < N ? row[0] : N - 1;
        row[1] = t*32 + 16 + l16; rc[1] = row[1] < N ? row[1] : N - 1;

        // ---- out-proj: A = wob8 (LDS), B = ctx8 (global fp8) ----
        f32x4 acc[2][8];
        #pragma unroll
        for (int mt = 0; mt < 2; ++mt)
            #pragma unroll
            for (int nt = 0; nt < 8; ++nt) acc[mt][nt] = (f32x4){0.f,0.f,0.f,0.f};
        {
            long cf[2][4];
            #pragma unroll
            for (int mt = 0; mt < 2; ++mt)
                #pragma unroll
                for (int c = 0; c < 4; ++c)
                    cf[mt][c] = *(const long*)(ctx8 + (size_t)rc[mt]*256 + c*32 + l4*8);
            #pragma unroll
            for (int nt = 0; nt < 8; ++nt) {
                #pragma unroll
                for (int c = 0; c < 4; ++c) {
                    long wf = *(const long*)(smem + (nt*16 + l16)*128 + (((c*4 + l4) ^ l16) << 3));
                    acc[0][nt] = __builtin_amdgcn_mfma_f32_16x16x32_fp8_fp8(wf, cf[0][c], acc[0][nt], 0, 0, 0);
                    acc[1][nt] = __builtin_amdgcn_mfma_f32_16x16x32_fp8_fp8(wf, cf[1][c], acc[1][nt], 0, 0, 0);
                }
            }
        }

        // ---- bias + x residual + LN1 ----
        float sum0 = 0.f, sq0 = 0.f, sum1 = 0.f, sq1 = 0.f;
        #pragma unroll
        for (int nt = 0; nt < 8; ++nt) {
            f32x4 obv = *(const f32x4*)(ob + nt*16 + l4*4);
            uint2 xr0 = *(const uint2*)(xb + (size_t)rc[0]*128 + nt*16 + l4*4);
            uint2 xr1 = *(const uint2*)(xb + (size_t)rc[1]*128 + nt*16 + l4*4);
            acc[0][nt][0] = acc[0][nt][0]*(1.f/128.f) + obv[0] + bflo(xr0.x);
            acc[0][nt][1] = acc[0][nt][1]*(1.f/128.f) + obv[1] + bfhi(xr0.x);
            acc[0][nt][2] = acc[0][nt][2]*(1.f/128.f) + obv[2] + bflo(xr0.y);
            acc[0][nt][3] = acc[0][nt][3]*(1.f/128.f) + obv[3] + bfhi(xr0.y);
            acc[1][nt][0] = acc[1][nt][0]*(1.f/128.f) + obv[0] + bflo(xr1.x);
            acc[1][nt][1] = acc[1][nt][1]*(1.f/128.f) + obv[1] + bfhi(xr1.x);
            acc[1][nt][2] = acc[1][nt][2]*(1.f/128.f) + obv[2] + bflo(xr1.y);
            acc[1][nt][3] = acc[1][nt][3]*(1.f/128.f) + obv[3] + bfhi(xr1.y);
            #pragma unroll
            for (int r = 0; r < 4; ++r) {
                sum0 += acc[0][nt][r]; sq0 += acc[0][nt][r]*acc[0][nt][r];
                sum1 += acc[1][nt][r]; sq1 += acc[1][nt][r]*acc[1][nt][r];
            }
        }
        sum0 += __shfl_xor(sum0, 16); sum0 += __shfl_xor(sum0, 32);
        sq0  += __shfl_xor(sq0, 16);  sq0  += __shfl_xor(sq0, 32);
        sum1 += __shfl_xor(sum1, 16); sum1 += __shfl_xor(sum1, 32);
        sq1  += __shfl_xor(sq1, 16);  sq1  += __shfl_xor(sq1, 32);
        float mean[2], rstd[2];
        mean[0] = sum0 * (1.f/128.f);
        rstd[0] = rsqrtf(sq0*(1.f/128.f) - mean[0]*mean[0] + EPS);
        mean[1] = sum1 * (1.f/128.f);
        rstd[1] = rsqrtf(sq1*(1.f/128.f) - mean[1]*mean[1] + EPS);

        // y -> bf16 (residual) + fp8 (MFMA B-operand)
        short8 yf16[2][4];
        long   yf8[2][4];
        #pragma unroll
        for (int mt = 0; mt < 2; ++mt) {
            #pragma unroll
            for (int c = 0; c < 4; ++c) {
                float yv[8];
                #pragma unroll
                for (int half = 0; half < 2; ++half) {
                    int nt = 2*c + half;
                    f32x4 gv = *(const f32x4*)(g1 + nt*16 + l4*4);
                    f32x4 bv = *(const f32x4*)(be1 + nt*16 + l4*4);
                    #pragma unroll
                    for (int r = 0; r < 4; ++r) {
                        float yn = (acc[mt][nt][r] - mean[mt]) * rstd[mt] * gv[r] + bv[r];
                        yv[half*4 + r] = yn;
                        yf16[mt][c][half*4 + r] = (short)f2bf(yn);
                    }
                }
                unsigned lo = pk4fp8(yv[0], yv[1], yv[2], yv[3]);
                unsigned hi = pk4fp8(yv[4], yv[5], yv[6], yv[7]);
                yf8[mt][c] = (long)(((unsigned long long)hi << 32) | lo);
            }
        }

        // ---- FFN: acc reused as acc2 (saves 64 VGPR vs fresh array) ----
        f32x4 (&acc2)[2][8] = acc;
        #pragma unroll
        for (int mt = 0; mt < 2; ++mt)
            #pragma unroll
            for (int nt = 0; nt < 8; ++nt) acc2[mt][nt] = (f32x4){0.f,0.f,0.f,0.f};
        #pragma unroll 4
        for (int kb = 0; kb < 16; ++kb) {
            const unsigned char* w1b = smem + 16384 + kb*4096;
            long wA[4], wB[4];
            #pragma unroll
            for (int c = 0; c < 4; ++c) {
                int so = ((c*4 + l4) ^ l16) << 3;
                wA[c] = *(const long*)(w1b + l16*128 + so);
                wB[c] = *(const long*)(w1b + (16 + l16)*128 + so);
            }
            f32x4 hA[2] = {{0.f,0.f,0.f,0.f},{0.f,0.f,0.f,0.f}};
            f32x4 hB[2] = {{0.f,0.f,0.f,0.f},{0.f,0.f,0.f,0.f}};
            #pragma unroll
            for (int c = 0; c < 4; ++c)
                #pragma unroll
                for (int mt = 0; mt < 2; ++mt) {
                    hA[mt] = __builtin_amdgcn_mfma_f32_16x16x32_fp8_fp8(wA[c], yf8[mt][c], hA[mt], 0, 0, 0);
                    hB[mt] = __builtin_amdgcn_mfma_f32_16x16x32_fp8_fp8(wB[c], yf8[mt][c], hB[mt], 0, 0, 0);
                }
            f32x4 bA = *(const f32x4*)(b1 + kb*32 + l4*4);
            f32x4 bB = *(const f32x4*)(b1 + kb*32 + 16 + l4*4);
            long hf8[2];
            #pragma unroll
            for (int mt = 0; mt < 2; ++mt) {
                float vA[4], vB[4];
                #pragma unroll
                for (int r = 0; r < 4; ++r) {
                    vA[r] = fmaxf(hA[mt][r]*0.0625f + bA[r], 0.f);
                    vB[r] = fmaxf(hB[mt][r]*0.0625f + bB[r], 0.f);
                }
                unsigned lo = pk4fp8(vA[0], vA[1], vA[2], vA[3]);
                unsigned hi = pk4fp8(vB[0], vB[1], vB[2], vB[3]);
                hf8[mt] = (long)(((unsigned long long)hi << 32) | lo);
            }
            const unsigned char* w2b = smem + 81920 + kb*4096 + l4*1024;
            #pragma unroll
            for (int nt = 0; nt < 8; ++nt) {
                long w2f = *(const long*)(w2b + (nt*16 + l16)*8);
                acc2[0][nt] = __builtin_amdgcn_mfma_f32_16x16x32_fp8_fp8(w2f, hf8[0], acc2[0][nt], 0, 0, 0);
                acc2[1][nt] = __builtin_amdgcn_mfma_f32_16x16x32_fp8_fp8(w2f, hf8[1], acc2[1][nt], 0, 0, 0);
            }
        }

        // ---- s = y + ff/16 + b2, LN2, store ----
        #pragma unroll
        for (int mt = 0; mt < 2; ++mt) {
            float sum2 = 0.f, sq2 = 0.f;
            #pragma unroll
            for (int nt = 0; nt < 8; ++nt) {
                f32x4 b2v = *(const f32x4*)(b2 + nt*16 + l4*4);
                #pragma unroll
                for (int r = 0; r < 4; ++r) {
                    float s = bf2f((ushort)yf16[mt][nt >> 1][(nt & 1)*4 + r])
                              + acc2[mt][nt][r]*0.0625f + b2v[r];
                    acc2[mt][nt][r] = s; sum2 += s; sq2 += s*s;
                }
            }
            sum2 += __shfl_xor(sum2, 16); sum2 += __shfl_xor(sum2, 32);
            sq2  += __shfl_xor(sq2, 16);  sq2  += __shfl_xor(sq2, 32);
            float mean2 = sum2 * (1.f/128.f);
            float rstd2 = rsqrtf(sq2*(1.f/128.f) - mean2*mean2 + EPS);
            if (row[mt] < N) {
                #pragma unroll
                for (int nt = 0; nt < 8; ++nt) {
                    f32x4 gv = *(const f32x4*)(g2 + nt*16 + l4*4);
                    f32x4 bv = *(const f32x4*)(be2 + nt*16 + l4*4);
                    f32x4 o;
                    #pragma unroll
                    for (int r = 0; r < 4; ++r)
                        o[r] = (acc2[mt][nt][r] - mean2) * rstd2 * gv[r] + bv[r];
                    *(f32x4*)(out + (size_t)row[mt]*128 + nt*16 + l4*4) = o;
                }
            }
        }
    }
}

extern "C" void kernel_launch(void* const* d_in, const int* in_sizes, int n_in,
                              void* d_out, int out_size, void* d_ws, size_t ws_size,
                              hipStream_t stream) {
    (void)n_in; (void)out_size; (void)ws_size;
    const float* x   = (const float*)d_in[0];
    const int*   smp = (const int*)  d_in[1];
    const float* ipw = (const float*)d_in[2];
    const float* ipb = (const float*)d_in[3];
    const float* ow  = (const float*)d_in[4];
    const float* ob  = (const float*)d_in[5];
    const float* w1  = (const float*)d_in[6];
    const float* b1  = (const float*)d_in[7];
    const float* w2  = (const float*)d_in[8];
    const float* b2  = (const float*)d_in[9];
    const float* g1  = (const float*)d_in[10];
    const float* be1 = (const float*)d_in[11];
    const float* g2  = (const float*)d_in[12];
    const float* be2 = (const float*)d_in[13];
    const int N = in_sizes[0] / 128;

    ushort* qt   = (ushort*)d_ws;                        // [N][128] bf16 q; ctx8 fp8 overlays
    unsigned char* kv8 = (unsigned char*)(qt + (size_t)N*128);   // [N][256] fp8 K|V
    ushort* wqb  = (ushort*)(kv8 + (size_t)N*256);       // 384*128 bf16
    unsigned char* wcat8 = (unsigned char*)(wqb + 49152);// 147456 B fp8 LDS image
    ushort* xb   = (ushort*)(wcat8 + 147456);            // [N][128] bf16 x
    float*  outp = (float*)d_out;

    k_prep <<<576,       256, 0, stream>>>(ipw, ow, w1, w2, wqb, wcat8);
    k_qkv  <<<(N+63)/64, 256, 0, stream>>>(x, wqb, ipb, qt, kv8, xb, N);
    k_attn <<<(N+3)/4,   256, 0, stream>>>(qt, kv8, smp, N);
    k_tail <<<256,       512, 0, stream>>>((const unsigned char*)qt, ob, xb, g1, be1,
                                           wcat8, b1, b2, g2, be2, outp, N);
}